// Round 3
// baseline (460.620 us; speedup 1.0000x reference)
//
#include <hip/hip_runtime.h>
#include <math.h>

typedef short v8s __attribute__((ext_vector_type(8)));
typedef float v4f __attribute__((ext_vector_type(4)));

#define EPS 1e-5f

__device__ __forceinline__ unsigned short f2bf(float x){
  unsigned u = __float_as_uint(x);
  return (unsigned short)((u + 0x7fffu + ((u>>16)&1u)) >> 16);
}
__device__ __forceinline__ float bf2f(unsigned short us){
  return __uint_as_float(((unsigned)us)<<16);
}

// ---------------------------------------------------------------------------
// K0: prep — G = W2 W2^T/768 (bf16), w2bar, u = W2 b2/768, b2bar, c0, W2T(bf16)
// ---------------------------------------------------------------------------
__global__ __launch_bounds__(256) void k_prep(const float* __restrict__ W2,
                                              const float* __restrict__ b2,
                                              unsigned short* __restrict__ Gm,
                                              float* __restrict__ w2bar,
                                              float* __restrict__ ubar,
                                              float* __restrict__ scal,
                                              unsigned short* __restrict__ W2T)
{
  __shared__ float row[768];
  __shared__ float part[256];
  int t = threadIdx.x;
  int blk = blockIdx.x;
  if (blk < 64){
    for (int c = t; c < 768; c += 256) row[c] = W2[blk*768 + c];
    __syncthreads();
    int jp = t & 63, quarter = t >> 6;
    float acc = 0.f;
    int c0 = quarter*192;
    for (int c = c0; c < c0+192; ++c) acc += row[c]*W2[jp*768 + c];
    part[t] = acc;
    __syncthreads();
    if (t < 64){
      float sv = part[t] + part[t+64] + part[t+128] + part[t+192];
      Gm[blk*64 + t] = f2bf(sv * (1.f/768.f));
    }
  } else if (blk == 64){
    if (t < 64){
      float sw=0.f, sus=0.f;
      for (int c=0;c<768;++c){ float wv=W2[t*768+c]; sw+=wv; sus+=wv*b2[c]; }
      w2bar[t]=sw*(1.f/768.f); ubar[t]=sus*(1.f/768.f);
    } else if (t == 64){
      float sb=0.f, sb2=0.f;
      for (int c=0;c<768;++c){ float v=b2[c]; sb+=v; sb2+=v*v; }
      scal[0]=sb*(1.f/768.f); scal[1]=sb2*(1.f/768.f);
    }
  } else {
    int bi = blk - 65;
    int c0 = bi*16;
    for (int idx = t; idx < 1024; idx += 256){
      int c = c0 + (idx >> 6), j = idx & 63;
      W2T[c*64 + j] = f2bf(W2[j*768 + c]);
    }
  }
}

// ---------------------------------------------------------------------------
// K1: exact KNN (top-9 by (d2, idx) lex == jax.lax.top_k tie rule) + geom.
// grid: B*64 = 256 blocks x 1024 threads. Scan: thread=(q in 64, chunk in 16),
// u64 keys (d2bits<<32|j), shared per-query threshold thrU[q] (atomicMin of
// each lane's 9th-best d2 bits) prunes ~60-75% of insertions. Exact: pruning
// only when d2bits > thr; a pruned true-top-9 key would imply 9 smaller keys
// already exist (contradiction). Merge: 16 lanes/query shfl_xor min-reduce.
// ---------------------------------------------------------------------------
__global__ __launch_bounds__(1024) void k_knn(const float* __restrict__ coords,
                                              float* __restrict__ geom)
{
#pragma clang fp contract(off)
  __shared__ float2 cxy[4096];                     // 32 KB
  __shared__ float  cz[4096];                      // 16 KB
  __shared__ unsigned long long keys[64][161];     // [q][c*10+s], pad -> 82.4 KB
  __shared__ unsigned int thrU[64];
  int t = threadIdx.x;
  int b  = blockIdx.x >> 6;
  int qb = blockIdx.x & 63;
  const float* cb = coords + (size_t)b*4096*3;
  for (int n = t; n < 4096; n += 1024){
    float x = cb[n*3+0], y = cb[n*3+1], z = cb[n*3+2];
    cxy[n] = make_float2(x, y); cz[n] = z;
  }
  if (t < 64) thrU[t] = 0xFFFFFFFFu;
  __syncthreads();

  int q = t & 63, c = t >> 6;
  int nq = qb*64 + q;
  float2 qxy = cxy[nq]; float qz = cz[nq];
  unsigned long long kv[9];
  #pragma unroll
  for (int i=0;i<9;++i) kv[i] = ~0ull;
  volatile unsigned int* thp = &thrU[q];
  int j0 = c*256;
  for (int jj=0; jj<256; ++jj){
    int j = j0 + jj;
    float2 pxy = cxy[j]; float pz = cz[j];
    float dx = pxy.x - qxy.x, dy = pxy.y - qxy.y, dz = pz - qz;
    float d2 = dx*dx; d2 = d2 + dy*dy; d2 = d2 + dz*dz;   // exact order as ref
    unsigned db = __float_as_uint(d2);
    unsigned long long key = ((unsigned long long)db << 32) | (unsigned)j;
    unsigned thr = *thp;
    bool ins = (key < kv[8]) & (db <= thr);
    if (__any(ins)){
      if (ins){
        kv[8] = key;
        #pragma unroll
        for (int i=8;i>0;--i){
          bool sw = kv[i] < kv[i-1];
          unsigned long long lo = sw ? kv[i] : kv[i-1];
          unsigned long long hi = sw ? kv[i-1] : kv[i];
          kv[i-1] = lo; kv[i] = hi;
        }
        atomicMin((unsigned int*)&thrU[q], (unsigned)(kv[8] >> 32));
      }
    }
  }
  // spill sorted lists (+inf pad in slot 9)
  unsigned long long* myrow = &keys[q][c*10];
  #pragma unroll
  for (int i=0;i<9;++i) myrow[i] = kv[i];
  myrow[9] = ~0ull;
  __syncthreads();

  // ---- parallel merge: 16 lanes per query, 9 picks, drop pick 0 ----
  int mq = t >> 4, mc = t & 15;
  int mnq = qb*64 + mq;
  float2 mqxy = cxy[mnq];
  unsigned long long* mrow = &keys[mq][mc*10];
  int pc = 0;
  unsigned long long head = mrow[0];
  float* outp = geom + ((size_t)(b*4096 + mnq))*32;   // 8 x 4 floats
  for (int pick=0; pick<9; ++pick){
    unsigned long long m = head;
    #pragma unroll
    for (int s=1; s<16; s<<=1){
      unsigned long long o = __shfl_xor(m, s, 16);
      m = (o < m) ? o : m;
    }
    bool winner = (head == m);       // keys unique -> exactly one lane
    if (winner){
      if (pick > 0){
        unsigned bi = (unsigned)(m & 0xFFFFFFFFu);
        float d2w = __uint_as_float((unsigned)(m >> 32));
        float2 nb = cxy[bi];
        float rx = nb.x - mqxy.x, ry = nb.y - mqxy.y;
        float rd = sqrtf(d2w);
        v4f g; g[0]=rd; g[1]=rx; g[2]=ry; g[3]=fminf(rd,1.0f);
        *reinterpret_cast<v4f*>(outp + (pick-1)*4) = g;
      }
      pc++;
      head = mrow[pc];
    }
  }
}

// ---------------------------------------------------------------------------
// K2: per-row h = relu(LN(geom@W1+b1)); z = h@G via MFMA; per-row m, inv;
//     h' = sum_k inv*h (bf16), S1 = sum inv, S2 = sum m*inv.
// grid: 512 blocks x 256 (256 rows/block = 32 points)
// ---------------------------------------------------------------------------
__global__ __launch_bounds__(256) void k_hbuild(
    const float* __restrict__ geom,
    const float* __restrict__ W1, const float* __restrict__ b1,
    const float* __restrict__ g1, const float* __restrict__ bt1,
    const unsigned short* __restrict__ Gm,
    const float* __restrict__ w2bar, const float* __restrict__ ubar,
    const float* __restrict__ scal,
    unsigned short* __restrict__ hprime, float* __restrict__ S1, float* __restrict__ S2)
{
  __shared__ v8s htile_v[256*8];          // 256 rows x 64 bf16, 16B-chunk XOR swizzle
  __shared__ __align__(16) float sW1[256];
  __shared__ __align__(16) float sb1[64], sg1[64], sbt1[64], swb[64], su[64];
  __shared__ float sinv[256], sminv[256];
  int t = threadIdx.x;
  sW1[t] = W1[t];
  if (t < 64){ sb1[t]=b1[t]; sg1[t]=g1[t]; sbt1[t]=bt1[t]; swb[t]=w2bar[t]; su[t]=ubar[t]; }
  int r0 = blockIdx.x * 256;
  v4f gv = reinterpret_cast<const v4f*>(geom)[r0 + t];
  __syncthreads();
  // ---- phase A: t1 = geom@W1+b1, LN(64), relu -> h (registers) ----
  float t1[64];
  #pragma unroll
  for (int l=0;l<64;l+=4){
    v4f w0 = *reinterpret_cast<const v4f*>(&sW1[l]);
    v4f w1 = *reinterpret_cast<const v4f*>(&sW1[64+l]);
    v4f w2 = *reinterpret_cast<const v4f*>(&sW1[128+l]);
    v4f w3 = *reinterpret_cast<const v4f*>(&sW1[192+l]);
    v4f bb = *reinterpret_cast<const v4f*>(&sb1[l]);
    #pragma unroll
    for (int e=0;e<4;++e)
      t1[l+e] = bb[e] + gv[0]*w0[e] + gv[1]*w1[e] + gv[2]*w2[e] + gv[3]*w3[e];
  }
  float s=0.f, s2=0.f;
  #pragma unroll
  for (int l=0;l<64;++l){ s += t1[l]; s2 += t1[l]*t1[l]; }
  float mu = s*(1.f/64.f);
  float var = s2*(1.f/64.f) - mu*mu;
  float inv = 1.0f/sqrtf(var+EPS);
  #pragma unroll
  for (int l=0;l<64;++l){
    float hv = (t1[l]-mu)*inv*sg1[l] + sbt1[l];
    t1[l] = hv > 0.f ? hv : 0.f;
  }
  #pragma unroll
  for (int cc=0;cc<8;++cc){
    v8s pk;
    #pragma unroll
    for (int e=0;e<8;++e) pk[e] = (short)f2bf(t1[cc*8+e]);
    htile_v[t*8 + (cc ^ (t&7))] = pk;
  }
  __syncthreads();
  // ---- phase B/C: z = h@G (MFMA), row stats ----
  int lane = t & 63, w = t >> 6;
  int l15 = lane & 15, l4 = lane >> 4;
  v8s gf[8];
  const v8s* Gv = reinterpret_cast<const v8s*>(Gm);   // G symmetric: row n gives B[k][n]
  #pragma unroll
  for (int tc=0;tc<4;++tc)
    #pragma unroll
    for (int kk=0;kk<2;++kk)
      gf[tc*2+kk] = Gv[(tc*16+l15)*8 + kk*4 + l4];
  float b2bar = scal[0], c0v = scal[1];
  const unsigned short* hs = reinterpret_cast<const unsigned short*>(htile_v);
  for (int rt = w; rt < 16; rt += 4){
    int arow = rt*16 + l15;
    v8s af0 = htile_v[arow*8 + ((l4)   ^ (arow&7))];
    v8s af1 = htile_v[arow*8 + ((4+l4) ^ (arow&7))];
    v4f acc[4];
    #pragma unroll
    for (int tc=0;tc<4;++tc){
      acc[tc] = (v4f){0.f,0.f,0.f,0.f};
      acc[tc] = __builtin_amdgcn_mfma_f32_16x16x32_bf16(af0, gf[tc*2+0], acc[tc], 0,0,0);
      acc[tc] = __builtin_amdgcn_mfma_f32_16x16x32_bf16(af1, gf[tc*2+1], acc[tc], 0,0,0);
    }
    float zh[4]={0,0,0,0}, hwb[4]={0,0,0,0}, hu[4]={0,0,0,0};
    #pragma unroll
    for (int r=0;r<4;++r){
      int row = rt*16 + l4*4 + r;
      #pragma unroll
      for (int tc=0;tc<4;++tc){
        int col = tc*16 + l15;
        int chunk = col >> 3;
        unsigned short us = hs[row*64 + ((chunk ^ (row&7))<<3) + (col&7)];
        float hval = bf2f(us);
        zh[r] += acc[tc][r]*hval;
        hwb[r] += hval*swb[col];
        hu[r]  += hval*su[col];
      }
    }
    #pragma unroll
    for (int mk=1; mk<16; mk<<=1){
      #pragma unroll
      for (int r=0;r<4;++r){
        zh[r] += __shfl_xor(zh[r], mk, 64);
        hwb[r]+= __shfl_xor(hwb[r],mk, 64);
        hu[r] += __shfl_xor(hu[r], mk, 64);
      }
    }
    if (l15 == 0){
      #pragma unroll
      for (int r=0;r<4;++r){
        int row = rt*16 + l4*4 + r;
        float mm = hwb[r] + b2bar;
        float vv = zh[r] + 2.f*hu[r] + c0v - mm*mm;
        float iv = 1.0f/sqrtf(vv + EPS);
        sinv[row]  = iv;
        sminv[row] = mm*iv;
      }
    }
  }
  __syncthreads();
  // ---- phase D: h' = sum_k inv*h ; S1,S2 ----
  int p = t >> 3, jg = t & 7;
  float hp[8] = {0,0,0,0,0,0,0,0};
  #pragma unroll
  for (int k=0;k<8;++k){
    int row = p*8 + k;
    float iv = sinv[row];
    v8s hv8 = htile_v[row*8 + (jg ^ (row&7))];
    #pragma unroll
    for (int e=0;e<8;++e) hp[e] += iv * bf2f((unsigned short)hv8[e]);
  }
  v8s pk;
  #pragma unroll
  for (int e=0;e<8;++e) pk[e] = (short)f2bf(hp[e]);
  int gp = blockIdx.x*32 + p;
  reinterpret_cast<v8s*>(hprime)[gp*8 + jg] = pk;
  if (jg == 0){
    float a=0.f, bb=0.f;
    #pragma unroll
    for (int k=0;k<8;++k){ a += sinv[p*8+k]; bb += sminv[p*8+k]; }
    S1[gp]=a; S2[gp]=bb;
  }
}

// ---------------------------------------------------------------------------
// K4: segment partial sums via LDS accumulators + float4 loads.
// grid: B(4) x NS(16 row-chunks of 256) x CC(3 col-chunks of 256) = 192 blocks
// ---------------------------------------------------------------------------
__global__ __launch_bounds__(256) void k_segsum(const float* __restrict__ features,
                                                const int* __restrict__ labels,
                                                float* __restrict__ partials,
                                                float* __restrict__ cntp)
{
  __shared__ float part[4][64][64];   // [e][seg][col-quad]; bank = cq&31 -> 2-way
  __shared__ int lab[256];
  __shared__ int lcnt[64];
  int t = threadIdx.x;
  int blk = blockIdx.x;
  int b = blk / 48;
  int rem = blk - b*48;
  int ns = rem / 3, cc = rem - ns*3;
  int n0 = ns*256, c0 = cc*256;
  float* pf = &part[0][0][0];
  for (int i=t;i<16384;i+=256) pf[i]=0.f;
  if (t<64) lcnt[t]=0;
  lab[t] = labels[b*4096 + n0 + t];
  __syncthreads();
  int rq = t>>6, cq = t&63;           // 4 row-slots x 64 col-quads (float4)
  const float* fb = features + (size_t)b*4096*768 + (size_t)n0*768 + c0 + cq*4;
  for (int itg=0; itg<64; itg+=4){
    v4f v[4]; int ss[4];
    #pragma unroll
    for (int u=0;u<4;++u){
      int row = (itg+u)*4 + rq;
      ss[u] = lab[row];
      v[u] = *reinterpret_cast<const v4f*>(fb + (size_t)row*768);
    }
    #pragma unroll
    for (int u=0;u<4;++u){
      #pragma unroll
      for (int e=0;e<4;++e)
        atomicAdd(&part[e][ss[u]][cq], v[u][e]);
    }
  }
  if (cc==0) atomicAdd(&lcnt[lab[t]], 1);
  __syncthreads();
  float* pb = partials + ((size_t)(b*16+ns)*64)*768 + c0;
  for (int i=t;i<16384;i+=256){
    int s = i>>8, c = i&255;
    pb[(size_t)s*768 + c] = part[c&3][s][c>>2];
  }
  if (cc==0 && t<64) cntp[(b*16+ns)*64 + t] = (float)lcnt[t];
}

// ---------------------------------------------------------------------------
// K5: reduce partials -> means; segment MLP; writes agg + total counts cntw
// grid: 256 blocks (one per (b,seg)) x 256
// ---------------------------------------------------------------------------
__global__ __launch_bounds__(256) void k_segmlp(const float* __restrict__ partials,
    const float* __restrict__ cntp,
    const float* __restrict__ A1, const float* __restrict__ ab1,
    const float* __restrict__ ag1, const float* __restrict__ abt1,
    const float* __restrict__ A2, const float* __restrict__ ab2,
    const float* __restrict__ ag2, const float* __restrict__ abt2,
    float* __restrict__ agg, float* __restrict__ cntw)
{
  __shared__ float meanr[768];
  __shared__ float ah[128];
  __shared__ float red[256];
  __shared__ float sstat[2];
  __shared__ float scnt;
  int t = threadIdx.x;
  int bs = blockIdx.x;
  int b = bs >> 6, sseg = bs & 63;
  if (t == 0){
    float c = 0.f;
    for (int ns=0;ns<16;++ns) c += cntp[(b*16+ns)*64 + sseg];
    scnt = c; cntw[bs] = c;
  }
  __syncthreads();
  float cv = scnt;
  float ic = 1.0f / fmaxf(cv, 1.0f);
  for (int i=t;i<768;i+=256){
    float acc = 0.f;
    #pragma unroll 4
    for (int ns=0;ns<16;++ns)
      acc += partials[((size_t)(b*16+ns)*64 + sseg)*768 + i];
    meanr[i] = acc*ic;
  }
  __syncthreads();
  float t1 = 0.f;
  if (t < 128){
    t1 = ab1[t];
    #pragma unroll 4
    for (int j=0;j<768;++j) t1 += meanr[j]*A1[j*128+t];
  }
  red[t] = (t<128) ? t1 : 0.f;
  __syncthreads();
  if (t == 0){
    float s=0.f, sq=0.f;
    for (int i=0;i<128;++i){ float v=red[i]; s+=v; sq+=v*v; }
    float mm = s*(1.f/128.f);
    sstat[0]=mm; sstat[1]=sq*(1.f/128.f)-mm*mm;
  }
  __syncthreads();
  if (t < 128){
    float iv = 1.0f/sqrtf(sstat[1]+EPS);
    float a = (t1-sstat[0])*iv*ag1[t] + abt1[t];
    ah[t] = fmaxf(a, 0.f);
  }
  __syncthreads();
  float o0 = ab2[t], o1 = ab2[t+256], o2 = ab2[t+512];
  #pragma unroll 4
  for (int j=0;j<128;++j){
    float hv = ah[j];
    o0 += hv*A2[j*768+t];
    o1 += hv*A2[j*768+t+256];
    o2 += hv*A2[j*768+t+512];
  }
  red[t] = o0+o1+o2;
  __syncthreads();
  if (t==0){ float s=0.f; for (int i=0;i<256;++i) s+=red[i]; sstat[0]=s*(1.f/768.f); }
  __syncthreads();
  red[t] = o0*o0+o1*o1+o2*o2;
  __syncthreads();
  if (t==0){ float s=0.f; for (int i=0;i<256;++i) s+=red[i]; sstat[1]=s*(1.f/768.f)-sstat[0]*sstat[0]; }
  __syncthreads();
  float iv = 1.0f/sqrtf(sstat[1]+EPS);
  float mm = sstat[0];
  agg[(size_t)bs*768 + t]       = (o0-mm)*iv*ag2[t]     + abt2[t];
  agg[(size_t)bs*768 + t + 256] = (o1-mm)*iv*ag2[t+256] + abt2[t+256];
  agg[(size_t)bs*768 + t + 512] = (o2-mm)*iv*ag2[t+512] + abt2[t+512];
}

// ---------------------------------------------------------------------------
// K3: ctx GEMM (h'@W2) + full epilogue -> out (fused final combine)
// grid: 256 blocks x 256 (64 rows/block, wave per 16-row tile, 48 col tiles)
// ---------------------------------------------------------------------------
__global__ __launch_bounds__(256) void k_final(
  const unsigned short* __restrict__ hprime, const unsigned short* __restrict__ W2T,
  const float* __restrict__ S1, const float* __restrict__ S2,
  const float* __restrict__ g2, const float* __restrict__ b2, const float* __restrict__ bt2,
  const float* __restrict__ features, const int* __restrict__ labels,
  const float* __restrict__ cnt, const float* __restrict__ agg,
  float* __restrict__ out)
{
  int t=threadIdx.x; int lane=t&63; int w=t>>6; int l15=lane&15, l4=lane>>4;
  int rowt = blockIdx.x*64 + w*16;
  const v8s* hv = reinterpret_cast<const v8s*>(hprime);
  v8s af0 = hv[(rowt+l15)*8 + l4];
  v8s af1 = hv[(rowt+l15)*8 + 4 + l4];
  float s1r[4], s2r[4], cntr[4]; int labr[4], br[4];
  #pragma unroll
  for (int r=0;r<4;++r){
    int row = rowt + l4*4 + r;
    s1r[r]=S1[row]; s2r[r]=S2[row];
    labr[r]=labels[row]; br[r]=row>>12;
    cntr[r]=cnt[br[r]*64 + labr[r]];
  }
  const v8s* wtv = reinterpret_cast<const v8s*>(W2T);
  for (int tc=0;tc<48;++tc){
    v8s bf0 = wtv[(tc*16+l15)*8 + l4];
    v8s bf1 = wtv[(tc*16+l15)*8 + 4 + l4];
    v4f acc = (v4f){0.f,0.f,0.f,0.f};
    acc = __builtin_amdgcn_mfma_f32_16x16x32_bf16(af0, bf0, acc, 0,0,0);
    acc = __builtin_amdgcn_mfma_f32_16x16x32_bf16(af1, bf1, acc, 0,0,0);
    int c = tc*16 + l15;
    float g2c=g2[c], b2c=b2[c], bt2c=bt2[c];
    #pragma unroll
    for (int r=0;r<4;++r){
      int row = rowt + l4*4 + r;
      float ctxv = 0.1f*(g2c*((acc[r] + b2c*s1r[r] - s2r[r])*0.125f) + bt2c);
      size_t o = (size_t)row*768 + c;
      float f = features[o];
      float av = agg[((size_t)(br[r]*64 + labr[r]))*768 + c];
      float enh = (cntr[r] >= 2.0f) ? (0.9f*f + 0.1f*av) : f;
      out[o] = enh + ctxv;
    }
  }
}

// ---------------------------------------------------------------------------
extern "C" void kernel_launch(void* const* d_in, const int* in_sizes, int n_in,
                              void* d_out, int out_size, void* d_ws, size_t ws_size,
                              hipStream_t stream) {
  const float* coords   = (const float*)d_in[0];
  const float* features = (const float*)d_in[1];
  const int*   labels   = (const int*)  d_in[2];
  const float* W1  = (const float*)d_in[3];
  const float* b1  = (const float*)d_in[4];
  const float* g1  = (const float*)d_in[5];
  const float* bt1 = (const float*)d_in[6];
  const float* W2  = (const float*)d_in[7];
  const float* b2  = (const float*)d_in[8];
  const float* g2  = (const float*)d_in[9];
  const float* bt2 = (const float*)d_in[10];
  const float* A1  = (const float*)d_in[11];
  const float* ab1 = (const float*)d_in[12];
  const float* ag1 = (const float*)d_in[13];
  const float* abt1= (const float*)d_in[14];
  const float* A2  = (const float*)d_in[15];
  const float* ab2 = (const float*)d_in[16];
  const float* ag2 = (const float*)d_in[17];
  const float* abt2= (const float*)d_in[18];

  char* ws = (char*)d_ws;
  size_t off = 0;
  auto alloc = [&](size_t bytes){ size_t o = off; off = (off + bytes + 255) & ~(size_t)255; return o; };
  // partials (12.6 MB) aliases geom (2 MB): lifetimes are disjoint on the
  // serial stream (segsum->segmlp complete before knn writes geom).
  char*           big    = ws + alloc((size_t)4*16*64*768*4);
  float*          partials = (float*)big;
  float*          geom     = (float*)big;
  unsigned short* hprime = (unsigned short*)(ws + alloc((size_t)16384*64*2));
  float*          S1w    = (float*)(ws + alloc(16384*4));
  float*          S2w    = (float*)(ws + alloc(16384*4));
  unsigned short* W2T    = (unsigned short*)(ws + alloc(768*64*2));
  unsigned short* Gm     = (unsigned short*)(ws + alloc(64*64*2));
  float*          w2bar  = (float*)(ws + alloc(64*4));
  float*          ubar   = (float*)(ws + alloc(64*4));
  float*          scal   = (float*)(ws + alloc(2*4));
  float*          cntp   = (float*)(ws + alloc(4*16*64*4));
  float*          cntw   = (float*)(ws + alloc(4*64*4));
  float*          agg    = (float*)(ws + alloc((size_t)4*64*768*4));

  k_prep  <<<dim3(113), dim3(256), 0, stream>>>(W2, b2, Gm, w2bar, ubar, scal, W2T);
  k_segsum<<<dim3(192), dim3(256), 0, stream>>>(features, labels, partials, cntp);
  k_segmlp<<<dim3(256), dim3(256), 0, stream>>>(partials, cntp, A1, ab1, ag1, abt1,
                                                A2, ab2, ag2, abt2, agg, cntw);
  k_knn   <<<dim3(256), dim3(1024),0, stream>>>(coords, geom);
  k_hbuild<<<dim3(512), dim3(256), 0, stream>>>(geom, W1, b1, g1, bt1, Gm, w2bar, ubar, scal,
                                                hprime, S1w, S2w);
  k_final <<<dim3(256), dim3(256), 0, stream>>>(hprime, W2T, S1w, S2w, g2, b2, bt2,
                                                features, labels, cntw, agg, (float*)d_out);
}

// Round 4
// 396.921 us; speedup vs baseline: 1.1605x; 1.1605x over previous
//
#include <hip/hip_runtime.h>
#include <math.h>

typedef short v8s __attribute__((ext_vector_type(8)));
typedef float v4f __attribute__((ext_vector_type(4)));

#define EPS 1e-5f

__device__ __forceinline__ unsigned short f2bf(float x){
  unsigned u = __float_as_uint(x);
  return (unsigned short)((u + 0x7fffu + ((u>>16)&1u)) >> 16);
}
__device__ __forceinline__ float bf2f(unsigned short us){
  return __uint_as_float(((unsigned)us)<<16);
}

// ---------------------------------------------------------------------------
// K0: prep — G = W2 W2^T/768 (bf16), w2bar, u = W2 b2/768, b2bar, c0, W2T(bf16)
// ---------------------------------------------------------------------------
__global__ __launch_bounds__(256) void k_prep(const float* __restrict__ W2,
                                              const float* __restrict__ b2,
                                              unsigned short* __restrict__ Gm,
                                              float* __restrict__ w2bar,
                                              float* __restrict__ ubar,
                                              float* __restrict__ scal,
                                              unsigned short* __restrict__ W2T)
{
  __shared__ float row[768];
  __shared__ float part[256];
  int t = threadIdx.x;
  int blk = blockIdx.x;
  if (blk < 64){
    for (int c = t; c < 768; c += 256) row[c] = W2[blk*768 + c];
    __syncthreads();
    int jp = t & 63, quarter = t >> 6;
    float acc = 0.f;
    int c0 = quarter*192;
    for (int c = c0; c < c0+192; ++c) acc += row[c]*W2[jp*768 + c];
    part[t] = acc;
    __syncthreads();
    if (t < 64){
      float sv = part[t] + part[t+64] + part[t+128] + part[t+192];
      Gm[blk*64 + t] = f2bf(sv * (1.f/768.f));
    }
  } else if (blk == 64){
    if (t < 64){
      float sw=0.f, sus=0.f;
      for (int c=0;c<768;++c){ float wv=W2[t*768+c]; sw+=wv; sus+=wv*b2[c]; }
      w2bar[t]=sw*(1.f/768.f); ubar[t]=sus*(1.f/768.f);
    } else if (t == 64){
      float sb=0.f, sb2=0.f;
      for (int c=0;c<768;++c){ float v=b2[c]; sb+=v; sb2+=v*v; }
      scal[0]=sb*(1.f/768.f); scal[1]=sb2*(1.f/768.f);
    }
  } else {
    int bi = blk - 65;
    int c0 = bi*16;
    for (int idx = t; idx < 1024; idx += 256){
      int c = c0 + (idx >> 6), j = idx & 63;
      W2T[c*64 + j] = f2bf(W2[j*768 + c]);
    }
  }
}

// ---------------------------------------------------------------------------
// K1: exact KNN, filter-then-select.
//  A) per-(q,chunk) lane: insertion top-9 over first 32 of its 256 cands
//  B) 16 lanes/q merge -> thr[q] = exact 9th-smallest key of the 512 samples
//     (>= true 9th of all 4096 -> pruning with it is exact)
//  C) hot scan: d2 + one u32 cmp; rare append (d2bits,idx) to compact list
//  D) 16 lanes/q: registers <=16 keys each; 9x (local-min>mprev + shfl
//     butterfly); lane0 writes geom. Overflow (cnt>256, P~1e-10): exact
//     in-kernel rescan fallback.
// Keys: (d2bits<<32)|idx == jax.lax.top_k (d2,idx) lex order. grid B*64.
// ---------------------------------------------------------------------------
__global__ __launch_bounds__(1024) void k_knn(const float* __restrict__ coords,
                                              float* __restrict__ geom)
{
#pragma clang fp contract(off)
  // LDS pool 147968 B: cxy f2[4096]@0 | cz f[4096]@32768 |
  //   listD u32[64][256]@49152 | listI u16[64][256]@114688 |
  //   spill u64[64*16*10]@49152 (aliases lists; dead before main scan) |
  //   thr u32[64]@147456 | cnt u32[64]@147712
  __shared__ __align__(16) char pool[147968];
  float2*             cxy   = (float2*)pool;
  float*              czp   = (float*)(pool + 32768);
  unsigned*           listD = (unsigned*)(pool + 49152);
  unsigned short*     listI = (unsigned short*)(pool + 114688);
  unsigned long long* spill = (unsigned long long*)(pool + 49152);
  unsigned*           thr   = (unsigned*)(pool + 147456);
  unsigned*           cnt   = (unsigned*)(pool + 147712);

  int t = threadIdx.x;
  int b  = blockIdx.x >> 6;
  int qb = blockIdx.x & 63;
  const float* cb = coords + (size_t)b*4096*3;
  for (int n = t; n < 4096; n += 1024){
    float x = cb[n*3+0], y = cb[n*3+1], z = cb[n*3+2];
    cxy[n] = make_float2(x, y); czp[n] = z;
  }
  if (t < 64) cnt[t] = 0;
  __syncthreads();

  int q = t & 63, c = t >> 6;
  int nq = qb*64 + q;
  float2 qxy = cxy[nq]; float qz = czp[nq];
  int j0 = c*256;

  // ---- A: sample top-9 of first 32 candidates of this chunk ----
  unsigned long long kv[9];
  #pragma unroll
  for (int i=0;i<9;++i) kv[i] = ~0ull;
  for (int jj=0; jj<32; ++jj){
    int j = j0 + jj;
    float2 pxy = cxy[j]; float pz = czp[j];
    float dx = pxy.x - qxy.x, dy = pxy.y - qxy.y, dz = pz - qz;
    float d2 = dx*dx; d2 = d2 + dy*dy; d2 = d2 + dz*dz;
    unsigned long long key = ((unsigned long long)__float_as_uint(d2) << 32) | (unsigned)j;
    if (key < kv[8]){
      kv[8] = key;
      #pragma unroll
      for (int i=8;i>0;--i){
        bool sw = kv[i] < kv[i-1];
        unsigned long long lo = sw ? kv[i] : kv[i-1];
        unsigned long long hi = sw ? kv[i-1] : kv[i];
        kv[i-1] = lo; kv[i] = hi;
      }
    }
  }
  {
    unsigned long long* srow = spill + ((q*16 + c)*10);
    #pragma unroll
    for (int i=0;i<9;++i) srow[i] = kv[i];
    srow[9] = ~0ull;
  }
  __syncthreads();

  // ---- B: thr[q] = 9th smallest of the 512 samples ----
  {
    int mq = t >> 4, mc = t & 15;
    unsigned long long* srow = spill + ((mq*16 + mc)*10);
    int pc = 0;
    unsigned long long head = srow[0];
    unsigned long long m = 0;
    for (int r=0; r<9; ++r){
      m = head;
      #pragma unroll
      for (int s=1; s<16; s<<=1){
        unsigned long long o = __shfl_xor(m, s, 16);
        m = (o < m) ? o : m;
      }
      if (head == m){ pc++; head = srow[pc]; }
    }
    if (mc == 0) thr[mq] = (unsigned)(m >> 32);
  }
  __syncthreads();   // spill dead; lists live from here

  // ---- C: hot scan — filter & append ----
  unsigned thrq = thr[q];
  for (int jj=0; jj<256; ++jj){
    int j = j0 + jj;
    float2 pxy = cxy[j]; float pz = czp[j];
    float dx = pxy.x - qxy.x, dy = pxy.y - qxy.y, dz = pz - qz;
    float d2 = dx*dx; d2 = d2 + dy*dy; d2 = d2 + dz*dz;
    unsigned db = __float_as_uint(d2);
    if (db <= thrq){
      unsigned pos = atomicAdd(&cnt[q], 1u);
      if (pos < 256u){
        listD[q*256 + pos] = db;
        listI[q*256 + pos] = (unsigned short)j;
      }
    }
  }
  __syncthreads();

  // ---- D: selection (16 lanes per query) ----
  int mq = t >> 4, mc = t & 15;
  unsigned craw = cnt[mq];
  unsigned cq = craw > 256u ? 256u : craw;
  unsigned long long key[16];
  #pragma unroll
  for (int i=0;i<16;++i){
    int slot = mc + i*16;
    if ((unsigned)slot < cq)
      key[i] = (((unsigned long long)listD[mq*256 + slot]) << 32) | listI[mq*256 + slot];
    else
      key[i] = ~0ull;
  }
  int mnq = qb*64 + mq;
  float2 mqxy = cxy[mnq];
  float* outp = geom + ((size_t)(b*4096 + mnq))*32;
  unsigned long long mprev = 0;
  for (int pick=0; pick<9; ++pick){
    unsigned long long lmin = ~0ull;
    #pragma unroll
    for (int i=0;i<16;++i){
      unsigned long long kk = key[i];
      bool ok = (pick == 0) | (kk > mprev);
      lmin = (ok && kk < lmin) ? kk : lmin;
    }
    unsigned long long m = lmin;
    #pragma unroll
    for (int s=1; s<16; s<<=1){
      unsigned long long o = __shfl_xor(m, s, 16);
      m = (o < m) ? o : m;
    }
    if (pick > 0 && mc == 0){
      unsigned bi = (unsigned)(m & 0xFFFFFFFFu);
      float d2w = __uint_as_float((unsigned)(m >> 32));
      float2 nb = cxy[bi];
      float rx = nb.x - mqxy.x, ry = nb.y - mqxy.y;
      float rd = sqrtf(d2w);
      v4f g; g[0]=rd; g[1]=rx; g[2]=ry; g[3]=fminf(rd,1.0f);
      *reinterpret_cast<v4f*>(outp + (pick-1)*4) = g;
    }
    mprev = m;
  }

  // ---- fallback: exact rescan for overflowed queries (P ~ 1e-10) ----
  bool fb = (craw > 256u);
  if (__any(fb)){
    if (fb){
      unsigned long long kv2[9];
      #pragma unroll
      for (int i=0;i<9;++i) kv2[i] = ~0ull;
      int jj0 = mc*256;
      for (int jj=0; jj<256; ++jj){
        int j = jj0 + jj;
        float2 pxy = cxy[j]; float pz = czp[j];
        float dx = pxy.x - mqxy.x, dy = pxy.y - mqxy.y, dz = pz - czp[mnq];
        float d2 = dx*dx; d2 = d2 + dy*dy; d2 = d2 + dz*dz;
        unsigned long long kkey = ((unsigned long long)__float_as_uint(d2) << 32) | (unsigned)j;
        if (kkey < kv2[8]){
          kv2[8] = kkey;
          #pragma unroll
          for (int i=8;i>0;--i){
            bool sw = kv2[i] < kv2[i-1];
            unsigned long long lo = sw ? kv2[i] : kv2[i-1];
            unsigned long long hi = sw ? kv2[i-1] : kv2[i];
            kv2[i-1] = lo; kv2[i] = hi;
          }
        }
      }
      int pc = 0;
      for (int pick=0; pick<9; ++pick){
        unsigned long long head = ~0ull;
        #pragma unroll
        for (int i=0;i<9;++i) head = (pc == i) ? kv2[i] : head;
        unsigned long long m = head;
        #pragma unroll
        for (int s=1; s<16; s<<=1){
          unsigned long long o = __shfl_xor(m, s, 16);
          m = (o < m) ? o : m;
        }
        if (head == m) pc++;
        if (pick > 0 && mc == 0){
          unsigned bi = (unsigned)(m & 0xFFFFFFFFu);
          float d2w = __uint_as_float((unsigned)(m >> 32));
          float2 nb = cxy[bi];
          float rx = nb.x - mqxy.x, ry = nb.y - mqxy.y;
          float rd = sqrtf(d2w);
          v4f g; g[0]=rd; g[1]=rx; g[2]=ry; g[3]=fminf(rd,1.0f);
          *reinterpret_cast<v4f*>(outp + (pick-1)*4) = g;
        }
      }
    }
  }
}

// ---------------------------------------------------------------------------
// K2: per-row h = relu(LN(geom@W1+b1)); z = h@G via MFMA; per-row m, inv;
//     h' = sum_k inv*h (bf16), S1 = sum inv, S2 = sum m*inv.
// grid: 512 blocks x 256 (256 rows/block = 32 points)
// ---------------------------------------------------------------------------
__global__ __launch_bounds__(256) void k_hbuild(
    const float* __restrict__ geom,
    const float* __restrict__ W1, const float* __restrict__ b1,
    const float* __restrict__ g1, const float* __restrict__ bt1,
    const unsigned short* __restrict__ Gm,
    const float* __restrict__ w2bar, const float* __restrict__ ubar,
    const float* __restrict__ scal,
    unsigned short* __restrict__ hprime, float* __restrict__ S1, float* __restrict__ S2)
{
  __shared__ v8s htile_v[256*8];          // 256 rows x 64 bf16, 16B-chunk XOR swizzle
  __shared__ __align__(16) float sW1[256];
  __shared__ __align__(16) float sb1[64], sg1[64], sbt1[64], swb[64], su[64];
  __shared__ float sinv[256], sminv[256];
  int t = threadIdx.x;
  sW1[t] = W1[t];
  if (t < 64){ sb1[t]=b1[t]; sg1[t]=g1[t]; sbt1[t]=bt1[t]; swb[t]=w2bar[t]; su[t]=ubar[t]; }
  int r0 = blockIdx.x * 256;
  v4f gv = reinterpret_cast<const v4f*>(geom)[r0 + t];
  __syncthreads();
  // ---- phase A: t1 = geom@W1+b1, LN(64), relu -> h (registers) ----
  float t1[64];
  #pragma unroll
  for (int l=0;l<64;l+=4){
    v4f w0 = *reinterpret_cast<const v4f*>(&sW1[l]);
    v4f w1 = *reinterpret_cast<const v4f*>(&sW1[64+l]);
    v4f w2 = *reinterpret_cast<const v4f*>(&sW1[128+l]);
    v4f w3 = *reinterpret_cast<const v4f*>(&sW1[192+l]);
    v4f bb = *reinterpret_cast<const v4f*>(&sb1[l]);
    #pragma unroll
    for (int e=0;e<4;++e)
      t1[l+e] = bb[e] + gv[0]*w0[e] + gv[1]*w1[e] + gv[2]*w2[e] + gv[3]*w3[e];
  }
  float s=0.f, s2=0.f;
  #pragma unroll
  for (int l=0;l<64;++l){ s += t1[l]; s2 += t1[l]*t1[l]; }
  float mu = s*(1.f/64.f);
  float var = s2*(1.f/64.f) - mu*mu;
  float inv = 1.0f/sqrtf(var+EPS);
  #pragma unroll
  for (int l=0;l<64;++l){
    float hv = (t1[l]-mu)*inv*sg1[l] + sbt1[l];
    t1[l] = hv > 0.f ? hv : 0.f;
  }
  #pragma unroll
  for (int cc=0;cc<8;++cc){
    v8s pk;
    #pragma unroll
    for (int e=0;e<8;++e) pk[e] = (short)f2bf(t1[cc*8+e]);
    htile_v[t*8 + (cc ^ (t&7))] = pk;
  }
  __syncthreads();
  // ---- phase B/C: z = h@G (MFMA), row stats ----
  int lane = t & 63, w = t >> 6;
  int l15 = lane & 15, l4 = lane >> 4;
  v8s gf[8];
  const v8s* Gv = reinterpret_cast<const v8s*>(Gm);   // G symmetric: row n gives B[k][n]
  #pragma unroll
  for (int tc=0;tc<4;++tc)
    #pragma unroll
    for (int kk=0;kk<2;++kk)
      gf[tc*2+kk] = Gv[(tc*16+l15)*8 + kk*4 + l4];
  float b2bar = scal[0], c0v = scal[1];
  const unsigned short* hs = reinterpret_cast<const unsigned short*>(htile_v);
  for (int rt = w; rt < 16; rt += 4){
    int arow = rt*16 + l15;
    v8s af0 = htile_v[arow*8 + ((l4)   ^ (arow&7))];
    v8s af1 = htile_v[arow*8 + ((4+l4) ^ (arow&7))];
    v4f acc[4];
    #pragma unroll
    for (int tc=0;tc<4;++tc){
      acc[tc] = (v4f){0.f,0.f,0.f,0.f};
      acc[tc] = __builtin_amdgcn_mfma_f32_16x16x32_bf16(af0, gf[tc*2+0], acc[tc], 0,0,0);
      acc[tc] = __builtin_amdgcn_mfma_f32_16x16x32_bf16(af1, gf[tc*2+1], acc[tc], 0,0,0);
    }
    float zh[4]={0,0,0,0}, hwb[4]={0,0,0,0}, hu[4]={0,0,0,0};
    #pragma unroll
    for (int r=0;r<4;++r){
      int row = rt*16 + l4*4 + r;
      #pragma unroll
      for (int tc=0;tc<4;++tc){
        int col = tc*16 + l15;
        int chunk = col >> 3;
        unsigned short us = hs[row*64 + ((chunk ^ (row&7))<<3) + (col&7)];
        float hval = bf2f(us);
        zh[r] += acc[tc][r]*hval;
        hwb[r] += hval*swb[col];
        hu[r]  += hval*su[col];
      }
    }
    #pragma unroll
    for (int mk=1; mk<16; mk<<=1){
      #pragma unroll
      for (int r=0;r<4;++r){
        zh[r] += __shfl_xor(zh[r], mk, 64);
        hwb[r]+= __shfl_xor(hwb[r],mk, 64);
        hu[r] += __shfl_xor(hu[r], mk, 64);
      }
    }
    if (l15 == 0){
      #pragma unroll
      for (int r=0;r<4;++r){
        int row = rt*16 + l4*4 + r;
        float mm = hwb[r] + b2bar;
        float vv = zh[r] + 2.f*hu[r] + c0v - mm*mm;
        float iv = 1.0f/sqrtf(vv + EPS);
        sinv[row]  = iv;
        sminv[row] = mm*iv;
      }
    }
  }
  __syncthreads();
  // ---- phase D: h' = sum_k inv*h ; S1,S2 ----
  int p = t >> 3, jg = t & 7;
  float hp[8] = {0,0,0,0,0,0,0,0};
  #pragma unroll
  for (int k=0;k<8;++k){
    int row = p*8 + k;
    float iv = sinv[row];
    v8s hv8 = htile_v[row*8 + (jg ^ (row&7))];
    #pragma unroll
    for (int e=0;e<8;++e) hp[e] += iv * bf2f((unsigned short)hv8[e]);
  }
  v8s pk;
  #pragma unroll
  for (int e=0;e<8;++e) pk[e] = (short)f2bf(hp[e]);
  int gp = blockIdx.x*32 + p;
  reinterpret_cast<v8s*>(hprime)[gp*8 + jg] = pk;
  if (jg == 0){
    float a=0.f, bb=0.f;
    #pragma unroll
    for (int k=0;k<8;++k){ a += sinv[p*8+k]; bb += sminv[p*8+k]; }
    S1[gp]=a; S2[gp]=bb;
  }
}

// ---------------------------------------------------------------------------
// K4: segment partial sums via LDS accumulators + float4 loads.
// grid: B(4) x NS(16 row-chunks of 256) x CC(3 col-chunks of 256) = 192 blocks
// ---------------------------------------------------------------------------
__global__ __launch_bounds__(256) void k_segsum(const float* __restrict__ features,
                                                const int* __restrict__ labels,
                                                float* __restrict__ partials,
                                                float* __restrict__ cntp)
{
  __shared__ float part[4][64][64];   // [e][seg][col-quad]; bank = cq&31 -> 2-way
  __shared__ int lab[256];
  __shared__ int lcnt[64];
  int t = threadIdx.x;
  int blk = blockIdx.x;
  int b = blk / 48;
  int rem = blk - b*48;
  int ns = rem / 3, cc = rem - ns*3;
  int n0 = ns*256, c0 = cc*256;
  float* pf = &part[0][0][0];
  for (int i=t;i<16384;i+=256) pf[i]=0.f;
  if (t<64) lcnt[t]=0;
  lab[t] = labels[b*4096 + n0 + t];
  __syncthreads();
  int rq = t>>6, cq = t&63;           // 4 row-slots x 64 col-quads (float4)
  const float* fb = features + (size_t)b*4096*768 + (size_t)n0*768 + c0 + cq*4;
  for (int itg=0; itg<64; itg+=4){
    v4f v[4]; int ss[4];
    #pragma unroll
    for (int u=0;u<4;++u){
      int row = (itg+u)*4 + rq;
      ss[u] = lab[row];
      v[u] = *reinterpret_cast<const v4f*>(fb + (size_t)row*768);
    }
    #pragma unroll
    for (int u=0;u<4;++u){
      #pragma unroll
      for (int e=0;e<4;++e)
        atomicAdd(&part[e][ss[u]][cq], v[u][e]);
    }
  }
  if (cc==0) atomicAdd(&lcnt[lab[t]], 1);
  __syncthreads();
  float* pb = partials + ((size_t)(b*16+ns)*64)*768 + c0;
  for (int i=t;i<16384;i+=256){
    int s = i>>8, c = i&255;
    pb[(size_t)s*768 + c] = part[c&3][s][c>>2];
  }
  if (cc==0 && t<64) cntp[(b*16+ns)*64 + t] = (float)lcnt[t];
}

// ---------------------------------------------------------------------------
// K5: reduce partials -> means; segment MLP; writes agg + total counts cntw
// grid: 256 blocks (one per (b,seg)) x 256
// ---------------------------------------------------------------------------
__global__ __launch_bounds__(256) void k_segmlp(const float* __restrict__ partials,
    const float* __restrict__ cntp,
    const float* __restrict__ A1, const float* __restrict__ ab1,
    const float* __restrict__ ag1, const float* __restrict__ abt1,
    const float* __restrict__ A2, const float* __restrict__ ab2,
    const float* __restrict__ ag2, const float* __restrict__ abt2,
    float* __restrict__ agg, float* __restrict__ cntw)
{
  __shared__ float meanr[768];
  __shared__ float ah[128];
  __shared__ float red[256];
  __shared__ float sstat[2];
  __shared__ float scnt;
  int t = threadIdx.x;
  int bs = blockIdx.x;
  int b = bs >> 6, sseg = bs & 63;
  if (t == 0){
    float c = 0.f;
    for (int ns=0;ns<16;++ns) c += cntp[(b*16+ns)*64 + sseg];
    scnt = c; cntw[bs] = c;
  }
  __syncthreads();
  float cv = scnt;
  float ic = 1.0f / fmaxf(cv, 1.0f);
  for (int i=t;i<768;i+=256){
    float acc = 0.f;
    #pragma unroll 4
    for (int ns=0;ns<16;++ns)
      acc += partials[((size_t)(b*16+ns)*64 + sseg)*768 + i];
    meanr[i] = acc*ic;
  }
  __syncthreads();
  float t1 = 0.f;
  if (t < 128){
    t1 = ab1[t];
    #pragma unroll 4
    for (int j=0;j<768;++j) t1 += meanr[j]*A1[j*128+t];
  }
  red[t] = (t<128) ? t1 : 0.f;
  __syncthreads();
  if (t == 0){
    float s=0.f, sq=0.f;
    for (int i=0;i<128;++i){ float v=red[i]; s+=v; sq+=v*v; }
    float mm = s*(1.f/128.f);
    sstat[0]=mm; sstat[1]=sq*(1.f/128.f)-mm*mm;
  }
  __syncthreads();
  if (t < 128){
    float iv = 1.0f/sqrtf(sstat[1]+EPS);
    float a = (t1-sstat[0])*iv*ag1[t] + abt1[t];
    ah[t] = fmaxf(a, 0.f);
  }
  __syncthreads();
  float o0 = ab2[t], o1 = ab2[t+256], o2 = ab2[t+512];
  #pragma unroll 4
  for (int j=0;j<128;++j){
    float hv = ah[j];
    o0 += hv*A2[j*768+t];
    o1 += hv*A2[j*768+t+256];
    o2 += hv*A2[j*768+t+512];
  }
  red[t] = o0+o1+o2;
  __syncthreads();
  if (t==0){ float s=0.f; for (int i=0;i<256;++i) s+=red[i]; sstat[0]=s*(1.f/768.f); }
  __syncthreads();
  red[t] = o0*o0+o1*o1+o2*o2;
  __syncthreads();
  if (t==0){ float s=0.f; for (int i=0;i<256;++i) s+=red[i]; sstat[1]=s*(1.f/768.f)-sstat[0]*sstat[0]; }
  __syncthreads();
  float iv = 1.0f/sqrtf(sstat[1]+EPS);
  float mm = sstat[0];
  agg[(size_t)bs*768 + t]       = (o0-mm)*iv*ag2[t]     + abt2[t];
  agg[(size_t)bs*768 + t + 256] = (o1-mm)*iv*ag2[t+256] + abt2[t+256];
  agg[(size_t)bs*768 + t + 512] = (o2-mm)*iv*ag2[t+512] + abt2[t+512];
}

// ---------------------------------------------------------------------------
// K3: ctx GEMM (h'@W2) + full epilogue -> out (fused final combine)
// grid: 256 blocks x 256 (64 rows/block, wave per 16-row tile, 48 col tiles)
// ---------------------------------------------------------------------------
__global__ __launch_bounds__(256) void k_final(
  const unsigned short* __restrict__ hprime, const unsigned short* __restrict__ W2T,
  const float* __restrict__ S1, const float* __restrict__ S2,
  const float* __restrict__ g2, const float* __restrict__ b2, const float* __restrict__ bt2,
  const float* __restrict__ features, const int* __restrict__ labels,
  const float* __restrict__ cnt, const float* __restrict__ agg,
  float* __restrict__ out)
{
  int t=threadIdx.x; int lane=t&63; int w=t>>6; int l15=lane&15, l4=lane>>4;
  int rowt = blockIdx.x*64 + w*16;
  const v8s* hv = reinterpret_cast<const v8s*>(hprime);
  v8s af0 = hv[(rowt+l15)*8 + l4];
  v8s af1 = hv[(rowt+l15)*8 + 4 + l4];
  float s1r[4], s2r[4], cntr[4]; int labr[4], br[4];
  #pragma unroll
  for (int r=0;r<4;++r){
    int row = rowt + l4*4 + r;
    s1r[r]=S1[row]; s2r[r]=S2[row];
    labr[r]=labels[row]; br[r]=row>>12;
    cntr[r]=cnt[br[r]*64 + labr[r]];
  }
  const v8s* wtv = reinterpret_cast<const v8s*>(W2T);
  for (int tc=0;tc<48;++tc){
    v8s bf0 = wtv[(tc*16+l15)*8 + l4];
    v8s bf1 = wtv[(tc*16+l15)*8 + 4 + l4];
    v4f acc = (v4f){0.f,0.f,0.f,0.f};
    acc = __builtin_amdgcn_mfma_f32_16x16x32_bf16(af0, bf0, acc, 0,0,0);
    acc = __builtin_amdgcn_mfma_f32_16x16x32_bf16(af1, bf1, acc, 0,0,0);
    int c = tc*16 + l15;
    float g2c=g2[c], b2c=b2[c], bt2c=bt2[c];
    #pragma unroll
    for (int r=0;r<4;++r){
      int row = rowt + l4*4 + r;
      float ctxv = 0.1f*(g2c*((acc[r] + b2c*s1r[r] - s2r[r])*0.125f) + bt2c);
      size_t o = (size_t)row*768 + c;
      float f = features[o];
      float av = agg[((size_t)(br[r]*64 + labr[r]))*768 + c];
      float enh = (cntr[r] >= 2.0f) ? (0.9f*f + 0.1f*av) : f;
      out[o] = enh + ctxv;
    }
  }
}

// ---------------------------------------------------------------------------
extern "C" void kernel_launch(void* const* d_in, const int* in_sizes, int n_in,
                              void* d_out, int out_size, void* d_ws, size_t ws_size,
                              hipStream_t stream) {
  const float* coords   = (const float*)d_in[0];
  const float* features = (const float*)d_in[1];
  const int*   labels   = (const int*)  d_in[2];
  const float* W1  = (const float*)d_in[3];
  const float* b1  = (const float*)d_in[4];
  const float* g1  = (const float*)d_in[5];
  const float* bt1 = (const float*)d_in[6];
  const float* W2  = (const float*)d_in[7];
  const float* b2  = (const float*)d_in[8];
  const float* g2  = (const float*)d_in[9];
  const float* bt2 = (const float*)d_in[10];
  const float* A1  = (const float*)d_in[11];
  const float* ab1 = (const float*)d_in[12];
  const float* ag1 = (const float*)d_in[13];
  const float* abt1= (const float*)d_in[14];
  const float* A2  = (const float*)d_in[15];
  const float* ab2 = (const float*)d_in[16];
  const float* ag2 = (const float*)d_in[17];
  const float* abt2= (const float*)d_in[18];

  char* ws = (char*)d_ws;
  size_t off = 0;
  auto alloc = [&](size_t bytes){ size_t o = off; off = (off + bytes + 255) & ~(size_t)255; return o; };
  // partials (12.6 MB) aliases geom (2 MB): lifetimes are disjoint on the
  // serial stream (segsum->segmlp complete before knn writes geom).
  char*           big    = ws + alloc((size_t)4*16*64*768*4);
  float*          partials = (float*)big;
  float*          geom     = (float*)big;
  unsigned short* hprime = (unsigned short*)(ws + alloc((size_t)16384*64*2));
  float*          S1w    = (float*)(ws + alloc(16384*4));
  float*          S2w    = (float*)(ws + alloc(16384*4));
  unsigned short* W2T    = (unsigned short*)(ws + alloc(768*64*2));
  unsigned short* Gm     = (unsigned short*)(ws + alloc(64*64*2));
  float*          w2bar  = (float*)(ws + alloc(64*4));
  float*          ubar   = (float*)(ws + alloc(64*4));
  float*          scal   = (float*)(ws + alloc(2*4));
  float*          cntp   = (float*)(ws + alloc(4*16*64*4));
  float*          cntw   = (float*)(ws + alloc(4*64*4));
  float*          agg    = (float*)(ws + alloc((size_t)4*64*768*4));

  k_prep  <<<dim3(113), dim3(256), 0, stream>>>(W2, b2, Gm, w2bar, ubar, scal, W2T);
  k_segsum<<<dim3(192), dim3(256), 0, stream>>>(features, labels, partials, cntp);
  k_segmlp<<<dim3(256), dim3(256), 0, stream>>>(partials, cntp, A1, ab1, ag1, abt1,
                                                A2, ab2, ag2, abt2, agg, cntw);
  k_knn   <<<dim3(256), dim3(1024),0, stream>>>(coords, geom);
  k_hbuild<<<dim3(512), dim3(256), 0, stream>>>(geom, W1, b1, g1, bt1, Gm, w2bar, ubar, scal,
                                                hprime, S1w, S2w);
  k_final <<<dim3(256), dim3(256), 0, stream>>>(hprime, W2T, S1w, S2w, g2, b2, bt2,
                                                features, labels, cntw, agg, (float*)d_out);
}

// Round 5
// 356.005 us; speedup vs baseline: 1.2939x; 1.1149x over previous
//
#include <hip/hip_runtime.h>
#include <math.h>

typedef short v8s __attribute__((ext_vector_type(8)));
typedef short v4sh __attribute__((ext_vector_type(4)));
typedef float v4f __attribute__((ext_vector_type(4)));

#define EPS 1e-5f

__device__ __forceinline__ unsigned short f2bf(float x){
  unsigned u = __float_as_uint(x);
  return (unsigned short)((u + 0x7fffu + ((u>>16)&1u)) >> 16);
}
__device__ __forceinline__ float bf2f(unsigned short us){
  return __uint_as_float(((unsigned)us)<<16);
}

// ---------------------------------------------------------------------------
// K0: prep — G = W2 W2^T/768 (bf16), w2bar, u = W2 b2/768, b2bar, c0, W2T(bf16),
//     A1bf/A2bf bf16 conversions.
// grid: 64 (G) + 1 (stats) + 48 (W2T) + 96 (A1bf) + 96 (A2bf) = 305 blocks
// ---------------------------------------------------------------------------
__global__ __launch_bounds__(256) void k_prep(const float* __restrict__ W2,
                                              const float* __restrict__ b2,
                                              unsigned short* __restrict__ Gm,
                                              float* __restrict__ w2bar,
                                              float* __restrict__ ubar,
                                              float* __restrict__ scal,
                                              unsigned short* __restrict__ W2T,
                                              const float* __restrict__ A1,
                                              const float* __restrict__ A2,
                                              unsigned short* __restrict__ A1bf,
                                              unsigned short* __restrict__ A2bf)
{
  __shared__ float row[768];
  __shared__ float part[256];
  int t = threadIdx.x;
  int blk = blockIdx.x;
  if (blk < 64){
    for (int c = t; c < 768; c += 256) row[c] = W2[blk*768 + c];
    __syncthreads();
    int jp = t & 63, quarter = t >> 6;
    float acc = 0.f;
    int c0 = quarter*192;
    for (int c = c0; c < c0+192; ++c) acc += row[c]*W2[jp*768 + c];
    part[t] = acc;
    __syncthreads();
    if (t < 64){
      float sv = part[t] + part[t+64] + part[t+128] + part[t+192];
      Gm[blk*64 + t] = f2bf(sv * (1.f/768.f));
    }
  } else if (blk == 64){
    if (t < 64){
      float sw=0.f, sus=0.f;
      for (int c=0;c<768;++c){ float wv=W2[t*768+c]; sw+=wv; sus+=wv*b2[c]; }
      w2bar[t]=sw*(1.f/768.f); ubar[t]=sus*(1.f/768.f);
    } else if (t == 64){
      float sb=0.f, sb2=0.f;
      for (int c=0;c<768;++c){ float v=b2[c]; sb+=v; sb2+=v*v; }
      scal[0]=sb*(1.f/768.f); scal[1]=sb2*(1.f/768.f);
    }
  } else if (blk < 113){
    int bi = blk - 65;
    int c0 = bi*16;
    for (int idx = t; idx < 1024; idx += 256){
      int c = c0 + (idx >> 6), j = idx & 63;
      W2T[c*64 + j] = f2bf(W2[j*768 + c]);
    }
  } else if (blk < 209){
    int base = (blk-113)*1024 + t*4;
    v4f v = *reinterpret_cast<const v4f*>(&A1[base]);
    v4sh p;
    #pragma unroll
    for (int e=0;e<4;++e) p[e] = (short)f2bf(v[e]);
    *reinterpret_cast<v4sh*>(&A1bf[base]) = p;
  } else {
    int base = (blk-209)*1024 + t*4;
    v4f v = *reinterpret_cast<const v4f*>(&A2[base]);
    v4sh p;
    #pragma unroll
    for (int e=0;e<4;++e) p[e] = (short)f2bf(v[e]);
    *reinterpret_cast<v4sh*>(&A2bf[base]) = p;
  }
}

// ---------------------------------------------------------------------------
// K1: exact KNN, filter-then-select (see R3 notes). grid B*64 x 1024.
// ---------------------------------------------------------------------------
__global__ __launch_bounds__(1024) void k_knn(const float* __restrict__ coords,
                                              float* __restrict__ geom)
{
#pragma clang fp contract(off)
  __shared__ __align__(16) char pool[147968];
  float2*             cxy   = (float2*)pool;
  float*              czp   = (float*)(pool + 32768);
  unsigned*           listD = (unsigned*)(pool + 49152);
  unsigned short*     listI = (unsigned short*)(pool + 114688);
  unsigned long long* spill = (unsigned long long*)(pool + 49152);
  unsigned*           thr   = (unsigned*)(pool + 147456);
  unsigned*           cnt   = (unsigned*)(pool + 147712);

  int t = threadIdx.x;
  int b  = blockIdx.x >> 6;
  int qb = blockIdx.x & 63;
  const float* cb = coords + (size_t)b*4096*3;
  for (int n = t; n < 4096; n += 1024){
    float x = cb[n*3+0], y = cb[n*3+1], z = cb[n*3+2];
    cxy[n] = make_float2(x, y); czp[n] = z;
  }
  if (t < 64) cnt[t] = 0;
  __syncthreads();

  int q = t & 63, c = t >> 6;
  int nq = qb*64 + q;
  float2 qxy = cxy[nq]; float qz = czp[nq];
  int j0 = c*256;

  // ---- A: sample top-9 of first 32 candidates of this chunk ----
  unsigned long long kv[9];
  #pragma unroll
  for (int i=0;i<9;++i) kv[i] = ~0ull;
  for (int jj=0; jj<32; ++jj){
    int j = j0 + jj;
    float2 pxy = cxy[j]; float pz = czp[j];
    float dx = pxy.x - qxy.x, dy = pxy.y - qxy.y, dz = pz - qz;
    float d2 = dx*dx; d2 = d2 + dy*dy; d2 = d2 + dz*dz;
    unsigned long long key = ((unsigned long long)__float_as_uint(d2) << 32) | (unsigned)j;
    if (key < kv[8]){
      kv[8] = key;
      #pragma unroll
      for (int i=8;i>0;--i){
        bool sw = kv[i] < kv[i-1];
        unsigned long long lo = sw ? kv[i] : kv[i-1];
        unsigned long long hi = sw ? kv[i-1] : kv[i];
        kv[i-1] = lo; kv[i] = hi;
      }
    }
  }
  {
    unsigned long long* srow = spill + ((q*16 + c)*10);
    #pragma unroll
    for (int i=0;i<9;++i) srow[i] = kv[i];
    srow[9] = ~0ull;
  }
  __syncthreads();

  // ---- B: thr[q] = 9th smallest of the 512 samples ----
  {
    int mq = t >> 4, mc = t & 15;
    unsigned long long* srow = spill + ((mq*16 + mc)*10);
    int pc = 0;
    unsigned long long head = srow[0];
    unsigned long long m = 0;
    for (int r=0; r<9; ++r){
      m = head;
      #pragma unroll
      for (int s=1; s<16; s<<=1){
        unsigned long long o = __shfl_xor(m, s, 16);
        m = (o < m) ? o : m;
      }
      if (head == m){ pc++; head = srow[pc]; }
    }
    if (mc == 0) thr[mq] = (unsigned)(m >> 32);
  }
  __syncthreads();   // spill dead; lists live from here

  // ---- C: hot scan — filter & append ----
  unsigned thrq = thr[q];
  for (int jj=0; jj<256; ++jj){
    int j = j0 + jj;
    float2 pxy = cxy[j]; float pz = czp[j];
    float dx = pxy.x - qxy.x, dy = pxy.y - qxy.y, dz = pz - qz;
    float d2 = dx*dx; d2 = d2 + dy*dy; d2 = d2 + dz*dz;
    unsigned db = __float_as_uint(d2);
    if (db <= thrq){
      unsigned pos = atomicAdd(&cnt[q], 1u);
      if (pos < 256u){
        listD[q*256 + pos] = db;
        listI[q*256 + pos] = (unsigned short)j;
      }
    }
  }
  __syncthreads();

  // ---- D: selection (16 lanes per query) ----
  int mq = t >> 4, mc = t & 15;
  unsigned craw = cnt[mq];
  unsigned cq = craw > 256u ? 256u : craw;
  unsigned long long key[16];
  #pragma unroll
  for (int i=0;i<16;++i){
    int slot = mc + i*16;
    if ((unsigned)slot < cq)
      key[i] = (((unsigned long long)listD[mq*256 + slot]) << 32) | listI[mq*256 + slot];
    else
      key[i] = ~0ull;
  }
  int mnq = qb*64 + mq;
  float2 mqxy = cxy[mnq];
  float* outp = geom + ((size_t)(b*4096 + mnq))*32;
  unsigned long long mprev = 0;
  for (int pick=0; pick<9; ++pick){
    unsigned long long lmin = ~0ull;
    #pragma unroll
    for (int i=0;i<16;++i){
      unsigned long long kk = key[i];
      bool ok = (pick == 0) | (kk > mprev);
      lmin = (ok && kk < lmin) ? kk : lmin;
    }
    unsigned long long m = lmin;
    #pragma unroll
    for (int s=1; s<16; s<<=1){
      unsigned long long o = __shfl_xor(m, s, 16);
      m = (o < m) ? o : m;
    }
    if (pick > 0 && mc == 0){
      unsigned bi = (unsigned)(m & 0xFFFFFFFFu);
      float d2w = __uint_as_float((unsigned)(m >> 32));
      float2 nb = cxy[bi];
      float rx = nb.x - mqxy.x, ry = nb.y - mqxy.y;
      float rd = sqrtf(d2w);
      v4f g; g[0]=rd; g[1]=rx; g[2]=ry; g[3]=fminf(rd,1.0f);
      *reinterpret_cast<v4f*>(outp + (pick-1)*4) = g;
    }
    mprev = m;
  }

  // ---- fallback: exact rescan for overflowed queries (P ~ 1e-10) ----
  bool fb = (craw > 256u);
  if (__any(fb)){
    if (fb){
      unsigned long long kv2[9];
      #pragma unroll
      for (int i=0;i<9;++i) kv2[i] = ~0ull;
      int jj0 = mc*256;
      for (int jj=0; jj<256; ++jj){
        int j = jj0 + jj;
        float2 pxy = cxy[j]; float pz = czp[j];
        float dx = pxy.x - mqxy.x, dy = pxy.y - mqxy.y, dz = pz - czp[mnq];
        float d2 = dx*dx; d2 = d2 + dy*dy; d2 = d2 + dz*dz;
        unsigned long long kkey = ((unsigned long long)__float_as_uint(d2) << 32) | (unsigned)j;
        if (kkey < kv2[8]){
          kv2[8] = kkey;
          #pragma unroll
          for (int i=8;i>0;--i){
            bool sw = kv2[i] < kv2[i-1];
            unsigned long long lo = sw ? kv2[i] : kv2[i-1];
            unsigned long long hi = sw ? kv2[i-1] : kv2[i];
            kv2[i-1] = lo; kv2[i] = hi;
          }
        }
      }
      int pc = 0;
      for (int pick=0; pick<9; ++pick){
        unsigned long long head = ~0ull;
        #pragma unroll
        for (int i=0;i<9;++i) head = (pc == i) ? kv2[i] : head;
        unsigned long long m = head;
        #pragma unroll
        for (int s=1; s<16; s<<=1){
          unsigned long long o = __shfl_xor(m, s, 16);
          m = (o < m) ? o : m;
        }
        if (head == m) pc++;
        if (pick > 0 && mc == 0){
          unsigned bi = (unsigned)(m & 0xFFFFFFFFu);
          float d2w = __uint_as_float((unsigned)(m >> 32));
          float2 nb = cxy[bi];
          float rx = nb.x - mqxy.x, ry = nb.y - mqxy.y;
          float rd = sqrtf(d2w);
          v4f g; g[0]=rd; g[1]=rx; g[2]=ry; g[3]=fminf(rd,1.0f);
          *reinterpret_cast<v4f*>(outp + (pick-1)*4) = g;
        }
      }
    }
  }
}

// ---------------------------------------------------------------------------
// K2: per-row h = relu(LN(geom@W1+b1)); z = h@G via MFMA; per-row m, inv;
//     h' = sum_k inv*h (bf16), S1 = sum inv, S2 = sum m*inv.
// grid: 512 blocks x 256 (256 rows/block = 32 points)
// ---------------------------------------------------------------------------
__global__ __launch_bounds__(256) void k_hbuild(
    const float* __restrict__ geom,
    const float* __restrict__ W1, const float* __restrict__ b1,
    const float* __restrict__ g1, const float* __restrict__ bt1,
    const unsigned short* __restrict__ Gm,
    const float* __restrict__ w2bar, const float* __restrict__ ubar,
    const float* __restrict__ scal,
    unsigned short* __restrict__ hprime, float* __restrict__ S1, float* __restrict__ S2)
{
  __shared__ v8s htile_v[256*8];          // 256 rows x 64 bf16, 16B-chunk XOR swizzle
  __shared__ __align__(16) float sW1[256];
  __shared__ __align__(16) float sb1[64], sg1[64], sbt1[64], swb[64], su[64];
  __shared__ float sinv[256], sminv[256];
  int t = threadIdx.x;
  sW1[t] = W1[t];
  if (t < 64){ sb1[t]=b1[t]; sg1[t]=g1[t]; sbt1[t]=bt1[t]; swb[t]=w2bar[t]; su[t]=ubar[t]; }
  int r0 = blockIdx.x * 256;
  v4f gv = reinterpret_cast<const v4f*>(geom)[r0 + t];
  __syncthreads();
  // ---- phase A: t1 = geom@W1+b1, LN(64), relu -> h (registers) ----
  float t1[64];
  #pragma unroll
  for (int l=0;l<64;l+=4){
    v4f w0 = *reinterpret_cast<const v4f*>(&sW1[l]);
    v4f w1 = *reinterpret_cast<const v4f*>(&sW1[64+l]);
    v4f w2 = *reinterpret_cast<const v4f*>(&sW1[128+l]);
    v4f w3 = *reinterpret_cast<const v4f*>(&sW1[192+l]);
    v4f bb = *reinterpret_cast<const v4f*>(&sb1[l]);
    #pragma unroll
    for (int e=0;e<4;++e)
      t1[l+e] = bb[e] + gv[0]*w0[e] + gv[1]*w1[e] + gv[2]*w2[e] + gv[3]*w3[e];
  }
  float s=0.f, s2=0.f;
  #pragma unroll
  for (int l=0;l<64;++l){ s += t1[l]; s2 += t1[l]*t1[l]; }
  float mu = s*(1.f/64.f);
  float var = s2*(1.f/64.f) - mu*mu;
  float inv = 1.0f/sqrtf(var+EPS);
  #pragma unroll
  for (int l=0;l<64;++l){
    float hv = (t1[l]-mu)*inv*sg1[l] + sbt1[l];
    t1[l] = hv > 0.f ? hv : 0.f;
  }
  #pragma unroll
  for (int cc=0;cc<8;++cc){
    v8s pk;
    #pragma unroll
    for (int e=0;e<8;++e) pk[e] = (short)f2bf(t1[cc*8+e]);
    htile_v[t*8 + (cc ^ (t&7))] = pk;
  }
  __syncthreads();
  // ---- phase B/C: z = h@G (MFMA), row stats ----
  int lane = t & 63, w = t >> 6;
  int l15 = lane & 15, l4 = lane >> 4;
  v8s gf[8];
  const v8s* Gv = reinterpret_cast<const v8s*>(Gm);   // G symmetric: row n gives B[k][n]
  #pragma unroll
  for (int tc=0;tc<4;++tc)
    #pragma unroll
    for (int kk=0;kk<2;++kk)
      gf[tc*2+kk] = Gv[(tc*16+l15)*8 + kk*4 + l4];
  float b2bar = scal[0], c0v = scal[1];
  const unsigned short* hs = reinterpret_cast<const unsigned short*>(htile_v);
  for (int rt = w; rt < 16; rt += 4){
    int arow = rt*16 + l15;
    v8s af0 = htile_v[arow*8 + ((l4)   ^ (arow&7))];
    v8s af1 = htile_v[arow*8 + ((4+l4) ^ (arow&7))];
    v4f acc[4];
    #pragma unroll
    for (int tc=0;tc<4;++tc){
      acc[tc] = (v4f){0.f,0.f,0.f,0.f};
      acc[tc] = __builtin_amdgcn_mfma_f32_16x16x32_bf16(af0, gf[tc*2+0], acc[tc], 0,0,0);
      acc[tc] = __builtin_amdgcn_mfma_f32_16x16x32_bf16(af1, gf[tc*2+1], acc[tc], 0,0,0);
    }
    float zh[4]={0,0,0,0}, hwb[4]={0,0,0,0}, hu[4]={0,0,0,0};
    #pragma unroll
    for (int r=0;r<4;++r){
      int row = rt*16 + l4*4 + r;
      #pragma unroll
      for (int tc=0;tc<4;++tc){
        int col = tc*16 + l15;
        int chunk = col >> 3;
        unsigned short us = hs[row*64 + ((chunk ^ (row&7))<<3) + (col&7)];
        float hval = bf2f(us);
        zh[r] += acc[tc][r]*hval;
        hwb[r] += hval*swb[col];
        hu[r]  += hval*su[col];
      }
    }
    #pragma unroll
    for (int mk=1; mk<16; mk<<=1){
      #pragma unroll
      for (int r=0;r<4;++r){
        zh[r] += __shfl_xor(zh[r], mk, 64);
        hwb[r]+= __shfl_xor(hwb[r],mk, 64);
        hu[r] += __shfl_xor(hu[r], mk, 64);
      }
    }
    if (l15 == 0){
      #pragma unroll
      for (int r=0;r<4;++r){
        int row = rt*16 + l4*4 + r;
        float mm = hwb[r] + b2bar;
        float vv = zh[r] + 2.f*hu[r] + c0v - mm*mm;
        float iv = 1.0f/sqrtf(vv + EPS);
        sinv[row]  = iv;
        sminv[row] = mm*iv;
      }
    }
  }
  __syncthreads();
  // ---- phase D: h' = sum_k inv*h ; S1,S2 ----
  int p = t >> 3, jg = t & 7;
  float hp[8] = {0,0,0,0,0,0,0,0};
  #pragma unroll
  for (int k=0;k<8;++k){
    int row = p*8 + k;
    float iv = sinv[row];
    v8s hv8 = htile_v[row*8 + (jg ^ (row&7))];
    #pragma unroll
    for (int e=0;e<8;++e) hp[e] += iv * bf2f((unsigned short)hv8[e]);
  }
  v8s pk;
  #pragma unroll
  for (int e=0;e<8;++e) pk[e] = (short)f2bf(hp[e]);
  int gp = blockIdx.x*32 + p;
  reinterpret_cast<v8s*>(hprime)[gp*8 + jg] = pk;
  if (jg == 0){
    float a=0.f, bb=0.f;
    #pragma unroll
    for (int k=0;k<8;++k){ a += sinv[p*8+k]; bb += sminv[p*8+k]; }
    S1[gp]=a; S2[gp]=bb;
  }
}

// ---------------------------------------------------------------------------
// K4: segment partial sums via LDS accumulators + float4 loads.
// grid: B(4) x NS(16 row-chunks of 256) x CC(3 col-chunks of 256) = 192 blocks
// ---------------------------------------------------------------------------
__global__ __launch_bounds__(256) void k_segsum(const float* __restrict__ features,
                                                const int* __restrict__ labels,
                                                float* __restrict__ partials,
                                                float* __restrict__ cntp)
{
  __shared__ float part[4][64][64];   // [e][seg][col-quad]; bank = cq&31 -> 2-way
  __shared__ int lab[256];
  __shared__ int lcnt[64];
  int t = threadIdx.x;
  int blk = blockIdx.x;
  int b = blk / 48;
  int rem = blk - b*48;
  int ns = rem / 3, cc = rem - ns*3;
  int n0 = ns*256, c0 = cc*256;
  float* pf = &part[0][0][0];
  for (int i=t;i<16384;i+=256) pf[i]=0.f;
  if (t<64) lcnt[t]=0;
  lab[t] = labels[b*4096 + n0 + t];
  __syncthreads();
  int rq = t>>6, cq = t&63;           // 4 row-slots x 64 col-quads (float4)
  const float* fb = features + (size_t)b*4096*768 + (size_t)n0*768 + c0 + cq*4;
  for (int itg=0; itg<64; itg+=4){
    v4f v[4]; int ss[4];
    #pragma unroll
    for (int u=0;u<4;++u){
      int row = (itg+u)*4 + rq;
      ss[u] = lab[row];
      v[u] = *reinterpret_cast<const v4f*>(fb + (size_t)row*768);
    }
    #pragma unroll
    for (int u=0;u<4;++u){
      #pragma unroll
      for (int e=0;e<4;++e)
        atomicAdd(&part[e][ss[u]][cq], v[u][e]);
    }
  }
  if (cc==0) atomicAdd(&lcnt[lab[t]], 1);
  __syncthreads();
  float* pb = partials + ((size_t)(b*16+ns)*64)*768 + c0;
  for (int i=t;i<16384;i+=256){
    int s = i>>8, c = i&255;
    pb[(size_t)s*768 + c] = part[c&3][s][c>>2];
  }
  if (cc==0 && t<64) cntp[(b*16+ns)*64 + t] = (float)lcnt[t];
}

// ---------------------------------------------------------------------------
// K5a: reduce partials -> means; GEMM1 (means@A1bf); LN(128)+relu -> ahbuf
// grid: 64 blocks x 256 (4 (b,seg) rows per block)
// ---------------------------------------------------------------------------
__global__ __launch_bounds__(256) void k_mlp1(
    const float* __restrict__ partials, const float* __restrict__ cntp,
    const unsigned short* __restrict__ A1bf, const float* __restrict__ ab1,
    const float* __restrict__ ag1, const float* __restrict__ abt1,
    unsigned short* __restrict__ ahbuf, float* __restrict__ cntw)
{
  __shared__ float mean4[4][768];     // 12 KB
  __shared__ float red[4][4][128];    // [kg][r][c] 8 KB
  __shared__ float t1s[4][128];       // 2 KB
  __shared__ float sic[4];
  int t = threadIdx.x;
  int b = blockIdx.x >> 4, sq = blockIdx.x & 15;
  int seg0 = sq*4;
  if (t < 4){
    float c = 0.f;
    for (int ns=0;ns<16;++ns) c += cntp[(b*16+ns)*64 + seg0 + t];
    cntw[b*64 + seg0 + t] = c;
    sic[t] = 1.0f / fmaxf(c, 1.0f);
  }
  __syncthreads();
  // partials reduce: 4 rows x 768 cols = 768 float4s over 16 ns slices
  #pragma unroll
  for (int g=0; g<3; ++g){
    int idx = t + g*256;              // 0..767
    int r = idx / 192, q4 = idx - r*192;
    v4f acc = (v4f){0.f,0.f,0.f,0.f};
    const float* pbase = partials + ((size_t)(b*16)*64 + seg0 + r)*768 + q4*4;
    #pragma unroll 4
    for (int ns=0; ns<16; ++ns){
      v4f v = *reinterpret_cast<const v4f*>(pbase + (size_t)ns*64*768);
      acc[0]+=v[0]; acc[1]+=v[1]; acc[2]+=v[2]; acc[3]+=v[3];
    }
    float ic = sic[r];
    mean4[r][q4*4+0]=acc[0]*ic; mean4[r][q4*4+1]=acc[1]*ic;
    mean4[r][q4*4+2]=acc[2]*ic; mean4[r][q4*4+3]=acc[3]*ic;
  }
  __syncthreads();
  // GEMM1: K split 4 ways; each thread: 2 cols x 4 rows
  int kg = t >> 6, lane = t & 63;
  const unsigned* A1u = (const unsigned*)A1bf;   // [768][64] packed col-pairs
  float acc0[4] = {0,0,0,0}, acc1[4] = {0,0,0,0};
  int jbeg = kg*192;
  #pragma unroll 8
  for (int j=jbeg; j<jbeg+192; ++j){
    unsigned u = A1u[j*64 + lane];
    float a0 = bf2f((unsigned short)(u & 0xffffu));
    float a1v = bf2f((unsigned short)(u >> 16));
    #pragma unroll
    for (int r=0;r<4;++r){
      float mv = mean4[r][j];
      acc0[r] += mv*a0; acc1[r] += mv*a1v;
    }
  }
  #pragma unroll
  for (int r=0;r<4;++r){
    red[kg][r][lane*2+0] = acc0[r];
    red[kg][r][lane*2+1] = acc1[r];
  }
  __syncthreads();
  #pragma unroll
  for (int o=0; o<2; ++o){
    int idx = t + o*256;   // 0..511
    int r = idx >> 7, c = idx & 127;
    t1s[r][c] = red[0][r][c]+red[1][r][c]+red[2][r][c]+red[3][r][c] + ab1[c];
  }
  __syncthreads();
  // LN(128) + relu: wave w handles row w
  int w = t >> 6;
  float x0 = t1s[w][lane], x1 = t1s[w][lane+64];
  float s = x0+x1, s2 = x0*x0+x1*x1;
  #pragma unroll
  for (int mk=1; mk<64; mk<<=1){
    s  += __shfl_xor(s, mk, 64);
    s2 += __shfl_xor(s2, mk, 64);
  }
  float mu = s*(1.f/128.f);
  float var = s2*(1.f/128.f) - mu*mu;
  float iv = 1.0f/sqrtf(var+EPS);
  float a0 = (x0-mu)*iv*ag1[lane]    + abt1[lane];
  float a1v= (x1-mu)*iv*ag1[lane+64] + abt1[lane+64];
  a0 = fmaxf(a0, 0.f); a1v = fmaxf(a1v, 0.f);
  int grow = b*64 + seg0 + w;
  ahbuf[grow*128 + lane]      = f2bf(a0);
  ahbuf[grow*128 + lane + 64] = f2bf(a1v);
}

// ---------------------------------------------------------------------------
// K5b: GEMM2 (ah@A2bf) + LN(768) -> agg. grid: 64 blocks x 256 (4 rows each)
// ---------------------------------------------------------------------------
__global__ __launch_bounds__(256) void k_mlp2(
    const unsigned short* __restrict__ ahbuf,
    const unsigned short* __restrict__ A2bf, const float* __restrict__ ab2,
    const float* __restrict__ ag2, const float* __restrict__ abt2,
    float* __restrict__ agg)
{
  __shared__ float ahl[4][128];       // 2 KB
  __shared__ float2 red[4][256];      // 8 KB
  __shared__ float2 sst[4];
  int t = threadIdx.x;
  int row0 = blockIdx.x*4;
  #pragma unroll
  for (int o=0;o<2;++o){
    int idx = t + o*256; int r = idx>>7, c = idx&127;
    ahl[r][c] = bf2f(ahbuf[(row0+r)*128 + c]);
  }
  __syncthreads();
  float acc[4][3];
  #pragma unroll
  for (int r=0;r<4;++r){ acc[r][0]=0.f; acc[r][1]=0.f; acc[r][2]=0.f; }
  #pragma unroll 4
  for (int j=0;j<128;++j){
    float f0 = bf2f(A2bf[j*768 + t]);
    float f1 = bf2f(A2bf[j*768 + t + 256]);
    float f2v= bf2f(A2bf[j*768 + t + 512]);
    #pragma unroll
    for (int r=0;r<4;++r){
      float av = ahl[r][j];
      acc[r][0] += av*f0; acc[r][1] += av*f1; acc[r][2] += av*f2v;
    }
  }
  float bb0=ab2[t], bb1=ab2[t+256], bb2=ab2[t+512];
  float o_[4][3];
  #pragma unroll
  for (int r=0;r<4;++r){
    o_[r][0]=acc[r][0]+bb0; o_[r][1]=acc[r][1]+bb1; o_[r][2]=acc[r][2]+bb2;
  }
  #pragma unroll
  for (int r=0;r<4;++r)
    red[r][t] = make_float2(o_[r][0]+o_[r][1]+o_[r][2],
                            o_[r][0]*o_[r][0]+o_[r][1]*o_[r][1]+o_[r][2]*o_[r][2]);
  __syncthreads();
  int w = t>>6, lane = t&63;
  float s=0.f, s2=0.f;
  #pragma unroll
  for (int i=0;i<4;++i){ float2 v = red[w][lane + i*64]; s += v.x; s2 += v.y; }
  #pragma unroll
  for (int mk=1; mk<64; mk<<=1){
    s  += __shfl_xor(s, mk, 64);
    s2 += __shfl_xor(s2, mk, 64);
  }
  if (lane == 0){
    float mu = s*(1.f/768.f);
    float var = s2*(1.f/768.f) - mu*mu;
    sst[w] = make_float2(mu, 1.0f/sqrtf(var+EPS));
  }
  __syncthreads();
  float g0=ag2[t], g1v=ag2[t+256], g2v=ag2[t+512];
  float c0=abt2[t], c1=abt2[t+256], c2=abt2[t+512];
  #pragma unroll
  for (int r=0;r<4;++r){
    float mu = sst[r].x, iv = sst[r].y;
    float* ap = agg + (size_t)(row0+r)*768;
    ap[t]     = (o_[r][0]-mu)*iv*g0 + c0;
    ap[t+256] = (o_[r][1]-mu)*iv*g1v + c1;
    ap[t+512] = (o_[r][2]-mu)*iv*g2v + c2;
  }
}

// ---------------------------------------------------------------------------
// K3: ctx GEMM (h'@W2) + full epilogue -> out (fused final combine)
// grid: 256 blocks x 256 (64 rows/block, wave per 16-row tile, 48 col tiles)
// ---------------------------------------------------------------------------
__global__ __launch_bounds__(256) void k_final(
  const unsigned short* __restrict__ hprime, const unsigned short* __restrict__ W2T,
  const float* __restrict__ S1, const float* __restrict__ S2,
  const float* __restrict__ g2, const float* __restrict__ b2, const float* __restrict__ bt2,
  const float* __restrict__ features, const int* __restrict__ labels,
  const float* __restrict__ cnt, const float* __restrict__ agg,
  float* __restrict__ out)
{
  int t=threadIdx.x; int lane=t&63; int w=t>>6; int l15=lane&15, l4=lane>>4;
  int rowt = blockIdx.x*64 + w*16;
  const v8s* hv = reinterpret_cast<const v8s*>(hprime);
  v8s af0 = hv[(rowt+l15)*8 + l4];
  v8s af1 = hv[(rowt+l15)*8 + 4 + l4];
  float s1r[4], s2r[4], cntr[4]; int labr[4], br[4];
  #pragma unroll
  for (int r=0;r<4;++r){
    int row = rowt + l4*4 + r;
    s1r[r]=S1[row]; s2r[r]=S2[row];
    labr[r]=labels[row]; br[r]=row>>12;
    cntr[r]=cnt[br[r]*64 + labr[r]];
  }
  const v8s* wtv = reinterpret_cast<const v8s*>(W2T);
  for (int tc=0;tc<48;++tc){
    v8s bf0 = wtv[(tc*16+l15)*8 + l4];
    v8s bf1 = wtv[(tc*16+l15)*8 + 4 + l4];
    v4f acc = (v4f){0.f,0.f,0.f,0.f};
    acc = __builtin_amdgcn_mfma_f32_16x16x32_bf16(af0, bf0, acc, 0,0,0);
    acc = __builtin_amdgcn_mfma_f32_16x16x32_bf16(af1, bf1, acc, 0,0,0);
    int c = tc*16 + l15;
    float g2c=g2[c], b2c=b2[c], bt2c=bt2[c];
    #pragma unroll
    for (int r=0;r<4;++r){
      int row = rowt + l4*4 + r;
      float ctxv = 0.1f*(g2c*((acc[r] + b2c*s1r[r] - s2r[r])*0.125f) + bt2c);
      size_t o = (size_t)row*768 + c;
      float f = features[o];
      float av = agg[((size_t)(br[r]*64 + labr[r]))*768 + c];
      float enh = (cntr[r] >= 2.0f) ? (0.9f*f + 0.1f*av) : f;
      out[o] = enh + ctxv;
    }
  }
}

// ---------------------------------------------------------------------------
extern "C" void kernel_launch(void* const* d_in, const int* in_sizes, int n_in,
                              void* d_out, int out_size, void* d_ws, size_t ws_size,
                              hipStream_t stream) {
  const float* coords   = (const float*)d_in[0];
  const float* features = (const float*)d_in[1];
  const int*   labels   = (const int*)  d_in[2];
  const float* W1  = (const float*)d_in[3];
  const float* b1  = (const float*)d_in[4];
  const float* g1  = (const float*)d_in[5];
  const float* bt1 = (const float*)d_in[6];
  const float* W2  = (const float*)d_in[7];
  const float* b2  = (const float*)d_in[8];
  const float* g2  = (const float*)d_in[9];
  const float* bt2 = (const float*)d_in[10];
  const float* A1  = (const float*)d_in[11];
  const float* ab1 = (const float*)d_in[12];
  const float* ag1 = (const float*)d_in[13];
  const float* abt1= (const float*)d_in[14];
  const float* A2  = (const float*)d_in[15];
  const float* ab2 = (const float*)d_in[16];
  const float* ag2 = (const float*)d_in[17];
  const float* abt2= (const float*)d_in[18];

  char* ws = (char*)d_ws;
  size_t off = 0;
  auto alloc = [&](size_t bytes){ size_t o = off; off = (off + bytes + 255) & ~(size_t)255; return o; };
  // partials (12.6 MB) aliases geom (2 MB): lifetimes are disjoint on the
  // serial stream (segsum->mlp1 complete before knn writes geom).
  char*           big    = ws + alloc((size_t)4*16*64*768*4);
  float*          partials = (float*)big;
  float*          geom     = (float*)big;
  unsigned short* hprime = (unsigned short*)(ws + alloc((size_t)16384*64*2));
  float*          S1w    = (float*)(ws + alloc(16384*4));
  float*          S2w    = (float*)(ws + alloc(16384*4));
  unsigned short* W2T    = (unsigned short*)(ws + alloc(768*64*2));
  unsigned short* Gm     = (unsigned short*)(ws + alloc(64*64*2));
  float*          w2bar  = (float*)(ws + alloc(64*4));
  float*          ubar   = (float*)(ws + alloc(64*4));
  float*          scal   = (float*)(ws + alloc(2*4));
  float*          cntp   = (float*)(ws + alloc(4*16*64*4));
  float*          cntw   = (float*)(ws + alloc(4*64*4));
  float*          agg    = (float*)(ws + alloc((size_t)4*64*768*4));
  unsigned short* A1bf   = (unsigned short*)(ws + alloc((size_t)98304*2));
  unsigned short* A2bf   = (unsigned short*)(ws + alloc((size_t)98304*2));
  unsigned short* ahbuf  = (unsigned short*)(ws + alloc((size_t)256*128*2));

  k_prep  <<<dim3(305), dim3(256), 0, stream>>>(W2, b2, Gm, w2bar, ubar, scal, W2T,
                                                A1, A2, A1bf, A2bf);
  k_segsum<<<dim3(192), dim3(256), 0, stream>>>(features, labels, partials, cntp);
  k_mlp1  <<<dim3(64),  dim3(256), 0, stream>>>(partials, cntp, A1bf, ab1, ag1, abt1,
                                                ahbuf, cntw);
  k_mlp2  <<<dim3(64),  dim3(256), 0, stream>>>(ahbuf, A2bf, ab2, ag2, abt2, agg);
  k_knn   <<<dim3(256), dim3(1024),0, stream>>>(coords, geom);
  k_hbuild<<<dim3(512), dim3(256), 0, stream>>>(geom, W1, b1, g1, bt1, Gm, w2bar, ubar, scal,
                                                hprime, S1w, S2w);
  k_final <<<dim3(256), dim3(256), 0, stream>>>(hprime, W2T, S1w, S2w, g2, b2, bt2,
                                                features, labels, cntw, agg, (float*)d_out);
}

// Round 6
// 280.291 us; speedup vs baseline: 1.6434x; 1.2701x over previous
//
#include <hip/hip_runtime.h>
#include <math.h>

typedef short v8s __attribute__((ext_vector_type(8)));
typedef short v4sh __attribute__((ext_vector_type(4)));
typedef float v4f __attribute__((ext_vector_type(4)));

#define EPS 1e-5f

__device__ __forceinline__ unsigned short f2bf(float x){
  unsigned u = __float_as_uint(x);
  return (unsigned short)((u + 0x7fffu + ((u>>16)&1u)) >> 16);
}
__device__ __forceinline__ float bf2f(unsigned short us){
  return __uint_as_float(((unsigned)us)<<16);
}

// ---------------------------------------------------------------------------
// K0: prep — G = W2 W2^T/768 (bf16), w2bar, u = W2 b2/768, b2bar, c0, W2T(bf16),
//     A1bf/A2bf bf16 conversions.
// grid: 64 (G) + 1 (stats) + 48 (W2T) + 96 (A1bf) + 96 (A2bf) = 305 blocks
// ---------------------------------------------------------------------------
__global__ __launch_bounds__(256) void k_prep(const float* __restrict__ W2,
                                              const float* __restrict__ b2,
                                              unsigned short* __restrict__ Gm,
                                              float* __restrict__ w2bar,
                                              float* __restrict__ ubar,
                                              float* __restrict__ scal,
                                              unsigned short* __restrict__ W2T,
                                              const float* __restrict__ A1,
                                              const float* __restrict__ A2,
                                              unsigned short* __restrict__ A1bf,
                                              unsigned short* __restrict__ A2bf)
{
  __shared__ float row[768];
  __shared__ float part[256];
  int t = threadIdx.x;
  int blk = blockIdx.x;
  if (blk < 64){
    for (int c = t; c < 768; c += 256) row[c] = W2[blk*768 + c];
    __syncthreads();
    int jp = t & 63, quarter = t >> 6;
    float acc = 0.f;
    int c0 = quarter*192;
    for (int c = c0; c < c0+192; ++c) acc += row[c]*W2[jp*768 + c];
    part[t] = acc;
    __syncthreads();
    if (t < 64){
      float sv = part[t] + part[t+64] + part[t+128] + part[t+192];
      Gm[blk*64 + t] = f2bf(sv * (1.f/768.f));
    }
  } else if (blk == 64){
    if (t < 64){
      float sw=0.f, sus=0.f;
      for (int c=0;c<768;++c){ float wv=W2[t*768+c]; sw+=wv; sus+=wv*b2[c]; }
      w2bar[t]=sw*(1.f/768.f); ubar[t]=sus*(1.f/768.f);
    } else if (t == 64){
      float sb=0.f, sb2=0.f;
      for (int c=0;c<768;++c){ float v=b2[c]; sb+=v; sb2+=v*v; }
      scal[0]=sb*(1.f/768.f); scal[1]=sb2*(1.f/768.f);
    }
  } else if (blk < 113){
    int bi = blk - 65;
    int c0 = bi*16;
    for (int idx = t; idx < 1024; idx += 256){
      int c = c0 + (idx >> 6), j = idx & 63;
      W2T[c*64 + j] = f2bf(W2[j*768 + c]);
    }
  } else if (blk < 209){
    int base = (blk-113)*1024 + t*4;
    v4f v = *reinterpret_cast<const v4f*>(&A1[base]);
    v4sh p;
    #pragma unroll
    for (int e=0;e<4;++e) p[e] = (short)f2bf(v[e]);
    *reinterpret_cast<v4sh*>(&A1bf[base]) = p;
  } else {
    int base = (blk-209)*1024 + t*4;
    v4f v = *reinterpret_cast<const v4f*>(&A2[base]);
    v4sh p;
    #pragma unroll
    for (int e=0;e<4;++e) p[e] = (short)f2bf(v[e]);
    *reinterpret_cast<v4sh*>(&A2bf[base]) = p;
  }
}

// ---------------------------------------------------------------------------
// K-sort: per-batch counting sort of superpoint labels.
// grid: 4 blocks x 256. Outputs: idxbuf[b][4096] (u16 rows grouped by seg),
// offs[b][64] (exclusive starts), cntw[b][64] (float counts).
// ---------------------------------------------------------------------------
__global__ __launch_bounds__(256) void k_sortidx(const int* __restrict__ labels,
                                                 unsigned short* __restrict__ idxbuf,
                                                 int* __restrict__ offs,
                                                 float* __restrict__ cntw)
{
  __shared__ int hist[64];
  __shared__ int base[64];
  __shared__ int lab[4096];
  int t = threadIdx.x;
  int b = blockIdx.x;
  if (t < 64) hist[t] = 0;
  __syncthreads();
  for (int i=t;i<4096;i+=256){
    int l = labels[b*4096 + i];
    lab[i] = l;
    atomicAdd(&hist[l], 1);
  }
  __syncthreads();
  if (t < 64){
    int v = hist[t];
    int x = v;
    #pragma unroll
    for (int d=1; d<64; d<<=1){
      int y = __shfl_up(x, d, 64);
      if (t >= d) x += y;
    }
    base[t] = x - v;
    offs[b*64 + t] = x - v;
    cntw[b*64 + t] = (float)v;
  }
  __syncthreads();
  for (int i=t;i<4096;i+=256){
    int pos = atomicAdd(&base[lab[i]], 1);
    idxbuf[b*4096 + pos] = (unsigned short)i;
  }
}

// ---------------------------------------------------------------------------
// K4: segment means, register accumulation over sorted row lists.
// grid: B(4) x S(64) x CC(3) = 768 blocks x 256. Each thread owns one column,
// sums its segment's rows (8-unrolled independent coalesced loads), writes
// mean = sum/max(cnt,1).
// ---------------------------------------------------------------------------
__global__ __launch_bounds__(256) void k_segsum2(const float* __restrict__ features,
                                                 const unsigned short* __restrict__ idxbuf,
                                                 const int* __restrict__ offs,
                                                 const float* __restrict__ cntw,
                                                 float* __restrict__ mean)
{
  __shared__ unsigned short ridx[4096];
  int t = threadIdx.x;
  int blk = blockIdx.x;
  int b = blk / 192;
  int rem = blk - b*192;
  int seg = rem / 3, cc = rem - seg*3;
  int off = offs[b*64 + seg];
  int n = (int)cntw[b*64 + seg];
  for (int i=t;i<n;i+=256) ridx[i] = idxbuf[b*4096 + off + i];
  __syncthreads();
  int col = cc*256 + t;
  const float* fb = features + (size_t)b*4096*768 + col;
  float acc = 0.f;
  int i = 0;
  for (; i+8<=n; i+=8){
    float v0 = fb[(size_t)ridx[i+0]*768];
    float v1 = fb[(size_t)ridx[i+1]*768];
    float v2 = fb[(size_t)ridx[i+2]*768];
    float v3 = fb[(size_t)ridx[i+3]*768];
    float v4 = fb[(size_t)ridx[i+4]*768];
    float v5 = fb[(size_t)ridx[i+5]*768];
    float v6 = fb[(size_t)ridx[i+6]*768];
    float v7 = fb[(size_t)ridx[i+7]*768];
    acc += v0+v1+v2+v3+v4+v5+v6+v7;
  }
  for (; i<n; ++i) acc += fb[(size_t)ridx[i]*768];
  mean[((size_t)(b*64 + seg))*768 + col] = acc / fmaxf((float)n, 1.f);
}

// ---------------------------------------------------------------------------
// K1: exact KNN, filter-then-select (see R3 notes). grid B*64 x 1024.
// ---------------------------------------------------------------------------
__global__ __launch_bounds__(1024) void k_knn(const float* __restrict__ coords,
                                              float* __restrict__ geom)
{
#pragma clang fp contract(off)
  __shared__ __align__(16) char pool[147968];
  float2*             cxy   = (float2*)pool;
  float*              czp   = (float*)(pool + 32768);
  unsigned*           listD = (unsigned*)(pool + 49152);
  unsigned short*     listI = (unsigned short*)(pool + 114688);
  unsigned long long* spill = (unsigned long long*)(pool + 49152);
  unsigned*           thr   = (unsigned*)(pool + 147456);
  unsigned*           cnt   = (unsigned*)(pool + 147712);

  int t = threadIdx.x;
  int b  = blockIdx.x >> 6;
  int qb = blockIdx.x & 63;
  const float* cb = coords + (size_t)b*4096*3;
  for (int n = t; n < 4096; n += 1024){
    float x = cb[n*3+0], y = cb[n*3+1], z = cb[n*3+2];
    cxy[n] = make_float2(x, y); czp[n] = z;
  }
  if (t < 64) cnt[t] = 0;
  __syncthreads();

  int q = t & 63, c = t >> 6;
  int nq = qb*64 + q;
  float2 qxy = cxy[nq]; float qz = czp[nq];
  int j0 = c*256;

  // ---- A: sample top-9 of first 32 candidates of this chunk ----
  unsigned long long kv[9];
  #pragma unroll
  for (int i=0;i<9;++i) kv[i] = ~0ull;
  for (int jj=0; jj<32; ++jj){
    int j = j0 + jj;
    float2 pxy = cxy[j]; float pz = czp[j];
    float dx = pxy.x - qxy.x, dy = pxy.y - qxy.y, dz = pz - qz;
    float d2 = dx*dx; d2 = d2 + dy*dy; d2 = d2 + dz*dz;
    unsigned long long key = ((unsigned long long)__float_as_uint(d2) << 32) | (unsigned)j;
    if (key < kv[8]){
      kv[8] = key;
      #pragma unroll
      for (int i=8;i>0;--i){
        bool sw = kv[i] < kv[i-1];
        unsigned long long lo = sw ? kv[i] : kv[i-1];
        unsigned long long hi = sw ? kv[i-1] : kv[i];
        kv[i-1] = lo; kv[i] = hi;
      }
    }
  }
  {
    unsigned long long* srow = spill + ((q*16 + c)*10);
    #pragma unroll
    for (int i=0;i<9;++i) srow[i] = kv[i];
    srow[9] = ~0ull;
  }
  __syncthreads();

  // ---- B: thr[q] = 9th smallest of the 512 samples ----
  {
    int mq = t >> 4, mc = t & 15;
    unsigned long long* srow = spill + ((mq*16 + mc)*10);
    int pc = 0;
    unsigned long long head = srow[0];
    unsigned long long m = 0;
    for (int r=0; r<9; ++r){
      m = head;
      #pragma unroll
      for (int s=1; s<16; s<<=1){
        unsigned long long o = __shfl_xor(m, s, 16);
        m = (o < m) ? o : m;
      }
      if (head == m){ pc++; head = srow[pc]; }
    }
    if (mc == 0) thr[mq] = (unsigned)(m >> 32);
  }
  __syncthreads();   // spill dead; lists live from here

  // ---- C: hot scan — filter & append ----
  unsigned thrq = thr[q];
  for (int jj=0; jj<256; ++jj){
    int j = j0 + jj;
    float2 pxy = cxy[j]; float pz = czp[j];
    float dx = pxy.x - qxy.x, dy = pxy.y - qxy.y, dz = pz - qz;
    float d2 = dx*dx; d2 = d2 + dy*dy; d2 = d2 + dz*dz;
    unsigned db = __float_as_uint(d2);
    if (db <= thrq){
      unsigned pos = atomicAdd(&cnt[q], 1u);
      if (pos < 256u){
        listD[q*256 + pos] = db;
        listI[q*256 + pos] = (unsigned short)j;
      }
    }
  }
  __syncthreads();

  // ---- D: selection (16 lanes per query) ----
  int mq = t >> 4, mc = t & 15;
  unsigned craw = cnt[mq];
  unsigned cq = craw > 256u ? 256u : craw;
  unsigned long long key[16];
  #pragma unroll
  for (int i=0;i<16;++i){
    int slot = mc + i*16;
    if ((unsigned)slot < cq)
      key[i] = (((unsigned long long)listD[mq*256 + slot]) << 32) | listI[mq*256 + slot];
    else
      key[i] = ~0ull;
  }
  int mnq = qb*64 + mq;
  float2 mqxy = cxy[mnq];
  float* outp = geom + ((size_t)(b*4096 + mnq))*32;
  unsigned long long mprev = 0;
  for (int pick=0; pick<9; ++pick){
    unsigned long long lmin = ~0ull;
    #pragma unroll
    for (int i=0;i<16;++i){
      unsigned long long kk = key[i];
      bool ok = (pick == 0) | (kk > mprev);
      lmin = (ok && kk < lmin) ? kk : lmin;
    }
    unsigned long long m = lmin;
    #pragma unroll
    for (int s=1; s<16; s<<=1){
      unsigned long long o = __shfl_xor(m, s, 16);
      m = (o < m) ? o : m;
    }
    if (pick > 0 && mc == 0){
      unsigned bi = (unsigned)(m & 0xFFFFFFFFu);
      float d2w = __uint_as_float((unsigned)(m >> 32));
      float2 nb = cxy[bi];
      float rx = nb.x - mqxy.x, ry = nb.y - mqxy.y;
      float rd = sqrtf(d2w);
      v4f g; g[0]=rd; g[1]=rx; g[2]=ry; g[3]=fminf(rd,1.0f);
      *reinterpret_cast<v4f*>(outp + (pick-1)*4) = g;
    }
    mprev = m;
  }

  // ---- fallback: exact rescan for overflowed queries (P ~ 1e-10) ----
  bool fb = (craw > 256u);
  if (__any(fb)){
    if (fb){
      unsigned long long kv2[9];
      #pragma unroll
      for (int i=0;i<9;++i) kv2[i] = ~0ull;
      int jj0 = mc*256;
      for (int jj=0; jj<256; ++jj){
        int j = jj0 + jj;
        float2 pxy = cxy[j]; float pz = czp[j];
        float dx = pxy.x - mqxy.x, dy = pxy.y - mqxy.y, dz = pz - czp[mnq];
        float d2 = dx*dx; d2 = d2 + dy*dy; d2 = d2 + dz*dz;
        unsigned long long kkey = ((unsigned long long)__float_as_uint(d2) << 32) | (unsigned)j;
        if (kkey < kv2[8]){
          kv2[8] = kkey;
          #pragma unroll
          for (int i=8;i>0;--i){
            bool sw = kv2[i] < kv2[i-1];
            unsigned long long lo = sw ? kv2[i] : kv2[i-1];
            unsigned long long hi = sw ? kv2[i-1] : kv2[i];
            kv2[i-1] = lo; kv2[i] = hi;
          }
        }
      }
      int pc = 0;
      for (int pick=0; pick<9; ++pick){
        unsigned long long head = ~0ull;
        #pragma unroll
        for (int i=0;i<9;++i) head = (pc == i) ? kv2[i] : head;
        unsigned long long m = head;
        #pragma unroll
        for (int s=1; s<16; s<<=1){
          unsigned long long o = __shfl_xor(m, s, 16);
          m = (o < m) ? o : m;
        }
        if (head == m) pc++;
        if (pick > 0 && mc == 0){
          unsigned bi = (unsigned)(m & 0xFFFFFFFFu);
          float d2w = __uint_as_float((unsigned)(m >> 32));
          float2 nb = cxy[bi];
          float rx = nb.x - mqxy.x, ry = nb.y - mqxy.y;
          float rd = sqrtf(d2w);
          v4f g; g[0]=rd; g[1]=rx; g[2]=ry; g[3]=fminf(rd,1.0f);
          *reinterpret_cast<v4f*>(outp + (pick-1)*4) = g;
        }
      }
    }
  }
}

// ---------------------------------------------------------------------------
// K2: per-row h = relu(LN(geom@W1+b1)); z = h@G via MFMA; per-row m, inv;
//     h' = sum_k inv*h (bf16), S1 = sum inv, S2 = sum m*inv.
// grid: 512 blocks x 256 (256 rows/block = 32 points)
// ---------------------------------------------------------------------------
__global__ __launch_bounds__(256) void k_hbuild(
    const float* __restrict__ geom,
    const float* __restrict__ W1, const float* __restrict__ b1,
    const float* __restrict__ g1, const float* __restrict__ bt1,
    const unsigned short* __restrict__ Gm,
    const float* __restrict__ w2bar, const float* __restrict__ ubar,
    const float* __restrict__ scal,
    unsigned short* __restrict__ hprime, float* __restrict__ S1, float* __restrict__ S2)
{
  __shared__ v8s htile_v[256*8];          // 256 rows x 64 bf16, 16B-chunk XOR swizzle
  __shared__ __align__(16) float sW1[256];
  __shared__ __align__(16) float sb1[64], sg1[64], sbt1[64], swb[64], su[64];
  __shared__ float sinv[256], sminv[256];
  int t = threadIdx.x;
  sW1[t] = W1[t];
  if (t < 64){ sb1[t]=b1[t]; sg1[t]=g1[t]; sbt1[t]=bt1[t]; swb[t]=w2bar[t]; su[t]=ubar[t]; }
  int r0 = blockIdx.x * 256;
  v4f gv = reinterpret_cast<const v4f*>(geom)[r0 + t];
  __syncthreads();
  // ---- phase A: t1 = geom@W1+b1, LN(64), relu -> h (registers) ----
  float t1[64];
  #pragma unroll
  for (int l=0;l<64;l+=4){
    v4f w0 = *reinterpret_cast<const v4f*>(&sW1[l]);
    v4f w1 = *reinterpret_cast<const v4f*>(&sW1[64+l]);
    v4f w2 = *reinterpret_cast<const v4f*>(&sW1[128+l]);
    v4f w3 = *reinterpret_cast<const v4f*>(&sW1[192+l]);
    v4f bb = *reinterpret_cast<const v4f*>(&sb1[l]);
    #pragma unroll
    for (int e=0;e<4;++e)
      t1[l+e] = bb[e] + gv[0]*w0[e] + gv[1]*w1[e] + gv[2]*w2[e] + gv[3]*w3[e];
  }
  float s=0.f, s2=0.f;
  #pragma unroll
  for (int l=0;l<64;++l){ s += t1[l]; s2 += t1[l]*t1[l]; }
  float mu = s*(1.f/64.f);
  float var = s2*(1.f/64.f) - mu*mu;
  float inv = 1.0f/sqrtf(var+EPS);
  #pragma unroll
  for (int l=0;l<64;++l){
    float hv = (t1[l]-mu)*inv*sg1[l] + sbt1[l];
    t1[l] = hv > 0.f ? hv : 0.f;
  }
  #pragma unroll
  for (int cc=0;cc<8;++cc){
    v8s pk;
    #pragma unroll
    for (int e=0;e<8;++e) pk[e] = (short)f2bf(t1[cc*8+e]);
    htile_v[t*8 + (cc ^ (t&7))] = pk;
  }
  __syncthreads();
  // ---- phase B/C: z = h@G (MFMA), row stats ----
  int lane = t & 63, w = t >> 6;
  int l15 = lane & 15, l4 = lane >> 4;
  v8s gf[8];
  const v8s* Gv = reinterpret_cast<const v8s*>(Gm);   // G symmetric: row n gives B[k][n]
  #pragma unroll
  for (int tc=0;tc<4;++tc)
    #pragma unroll
    for (int kk=0;kk<2;++kk)
      gf[tc*2+kk] = Gv[(tc*16+l15)*8 + kk*4 + l4];
  float b2bar = scal[0], c0v = scal[1];
  const unsigned short* hs = reinterpret_cast<const unsigned short*>(htile_v);
  for (int rt = w; rt < 16; rt += 4){
    int arow = rt*16 + l15;
    v8s af0 = htile_v[arow*8 + ((l4)   ^ (arow&7))];
    v8s af1 = htile_v[arow*8 + ((4+l4) ^ (arow&7))];
    v4f acc[4];
    #pragma unroll
    for (int tc=0;tc<4;++tc){
      acc[tc] = (v4f){0.f,0.f,0.f,0.f};
      acc[tc] = __builtin_amdgcn_mfma_f32_16x16x32_bf16(af0, gf[tc*2+0], acc[tc], 0,0,0);
      acc[tc] = __builtin_amdgcn_mfma_f32_16x16x32_bf16(af1, gf[tc*2+1], acc[tc], 0,0,0);
    }
    float zh[4]={0,0,0,0}, hwb[4]={0,0,0,0}, hu[4]={0,0,0,0};
    #pragma unroll
    for (int r=0;r<4;++r){
      int row = rt*16 + l4*4 + r;
      #pragma unroll
      for (int tc=0;tc<4;++tc){
        int col = tc*16 + l15;
        int chunk = col >> 3;
        unsigned short us = hs[row*64 + ((chunk ^ (row&7))<<3) + (col&7)];
        float hval = bf2f(us);
        zh[r] += acc[tc][r]*hval;
        hwb[r] += hval*swb[col];
        hu[r]  += hval*su[col];
      }
    }
    #pragma unroll
    for (int mk=1; mk<16; mk<<=1){
      #pragma unroll
      for (int r=0;r<4;++r){
        zh[r] += __shfl_xor(zh[r], mk, 64);
        hwb[r]+= __shfl_xor(hwb[r],mk, 64);
        hu[r] += __shfl_xor(hu[r], mk, 64);
      }
    }
    if (l15 == 0){
      #pragma unroll
      for (int r=0;r<4;++r){
        int row = rt*16 + l4*4 + r;
        float mm = hwb[r] + b2bar;
        float vv = zh[r] + 2.f*hu[r] + c0v - mm*mm;
        float iv = 1.0f/sqrtf(vv + EPS);
        sinv[row]  = iv;
        sminv[row] = mm*iv;
      }
    }
  }
  __syncthreads();
  // ---- phase D: h' = sum_k inv*h ; S1,S2 ----
  int p = t >> 3, jg = t & 7;
  float hp[8] = {0,0,0,0,0,0,0,0};
  #pragma unroll
  for (int k=0;k<8;++k){
    int row = p*8 + k;
    float iv = sinv[row];
    v8s hv8 = htile_v[row*8 + (jg ^ (row&7))];
    #pragma unroll
    for (int e=0;e<8;++e) hp[e] += iv * bf2f((unsigned short)hv8[e]);
  }
  v8s pk;
  #pragma unroll
  for (int e=0;e<8;++e) pk[e] = (short)f2bf(hp[e]);
  int gp = blockIdx.x*32 + p;
  reinterpret_cast<v8s*>(hprime)[gp*8 + jg] = pk;
  if (jg == 0){
    float a=0.f, bb=0.f;
    #pragma unroll
    for (int k=0;k<8;++k){ a += sinv[p*8+k]; bb += sminv[p*8+k]; }
    S1[gp]=a; S2[gp]=bb;
  }
}

// ---------------------------------------------------------------------------
// K5a: GEMM1 (mean@A1bf); LN(128)+relu -> ahbuf
// grid: 64 blocks x 256 (4 (b,seg) rows per block)
// ---------------------------------------------------------------------------
__global__ __launch_bounds__(256) void k_mlp1(
    const float* __restrict__ mean,
    const unsigned short* __restrict__ A1bf, const float* __restrict__ ab1,
    const float* __restrict__ ag1, const float* __restrict__ abt1,
    unsigned short* __restrict__ ahbuf)
{
  __shared__ float mean4[4][768];     // 12 KB
  __shared__ float red[4][4][128];    // [kg][r][c] 8 KB
  __shared__ float t1s[4][128];       // 2 KB
  int t = threadIdx.x;
  int row0 = blockIdx.x*4;
  #pragma unroll
  for (int g=0; g<3; ++g){
    int idx = t + g*256;              // 0..767
    int r = idx / 192, q4 = idx - r*192;
    v4f v = *reinterpret_cast<const v4f*>(mean + (size_t)(row0+r)*768 + q4*4);
    mean4[r][q4*4+0]=v[0]; mean4[r][q4*4+1]=v[1];
    mean4[r][q4*4+2]=v[2]; mean4[r][q4*4+3]=v[3];
  }
  __syncthreads();
  // GEMM1: K split 4 ways; each thread: 2 cols x 4 rows
  int kg = t >> 6, lane = t & 63;
  const unsigned* A1u = (const unsigned*)A1bf;   // [768][64] packed col-pairs
  float acc0[4] = {0,0,0,0}, acc1[4] = {0,0,0,0};
  int jbeg = kg*192;
  #pragma unroll 8
  for (int j=jbeg; j<jbeg+192; ++j){
    unsigned u = A1u[j*64 + lane];
    float a0 = bf2f((unsigned short)(u & 0xffffu));
    float a1v = bf2f((unsigned short)(u >> 16));
    #pragma unroll
    for (int r=0;r<4;++r){
      float mv = mean4[r][j];
      acc0[r] += mv*a0; acc1[r] += mv*a1v;
    }
  }
  #pragma unroll
  for (int r=0;r<4;++r){
    red[kg][r][lane*2+0] = acc0[r];
    red[kg][r][lane*2+1] = acc1[r];
  }
  __syncthreads();
  #pragma unroll
  for (int o=0; o<2; ++o){
    int idx = t + o*256;   // 0..511
    int r = idx >> 7, c = idx & 127;
    t1s[r][c] = red[0][r][c]+red[1][r][c]+red[2][r][c]+red[3][r][c] + ab1[c];
  }
  __syncthreads();
  // LN(128) + relu: wave w handles row w
  int w = t >> 6;
  float x0 = t1s[w][lane], x1 = t1s[w][lane+64];
  float s = x0+x1, s2 = x0*x0+x1*x1;
  #pragma unroll
  for (int mk=1; mk<64; mk<<=1){
    s  += __shfl_xor(s, mk, 64);
    s2 += __shfl_xor(s2, mk, 64);
  }
  float mu = s*(1.f/128.f);
  float var = s2*(1.f/128.f) - mu*mu;
  float iv = 1.0f/sqrtf(var+EPS);
  float a0 = (x0-mu)*iv*ag1[lane]    + abt1[lane];
  float a1v= (x1-mu)*iv*ag1[lane+64] + abt1[lane+64];
  a0 = fmaxf(a0, 0.f); a1v = fmaxf(a1v, 0.f);
  int grow = row0 + w;
  ahbuf[grow*128 + lane]      = f2bf(a0);
  ahbuf[grow*128 + lane + 64] = f2bf(a1v);
}

// ---------------------------------------------------------------------------
// K5b: GEMM2 (ah@A2bf) + LN(768) -> agg. grid: 64 blocks x 256 (4 rows each)
// ---------------------------------------------------------------------------
__global__ __launch_bounds__(256) void k_mlp2(
    const unsigned short* __restrict__ ahbuf,
    const unsigned short* __restrict__ A2bf, const float* __restrict__ ab2,
    const float* __restrict__ ag2, const float* __restrict__ abt2,
    float* __restrict__ agg)
{
  __shared__ float ahl[4][128];       // 2 KB
  __shared__ float2 red[4][256];      // 8 KB
  __shared__ float2 sst[4];
  int t = threadIdx.x;
  int row0 = blockIdx.x*4;
  #pragma unroll
  for (int o=0;o<2;++o){
    int idx = t + o*256; int r = idx>>7, c = idx&127;
    ahl[r][c] = bf2f(ahbuf[(row0+r)*128 + c]);
  }
  __syncthreads();
  float acc[4][3];
  #pragma unroll
  for (int r=0;r<4;++r){ acc[r][0]=0.f; acc[r][1]=0.f; acc[r][2]=0.f; }
  #pragma unroll 4
  for (int j=0;j<128;++j){
    float f0 = bf2f(A2bf[j*768 + t]);
    float f1 = bf2f(A2bf[j*768 + t + 256]);
    float f2v= bf2f(A2bf[j*768 + t + 512]);
    #pragma unroll
    for (int r=0;r<4;++r){
      float av = ahl[r][j];
      acc[r][0] += av*f0; acc[r][1] += av*f1; acc[r][2] += av*f2v;
    }
  }
  float bb0=ab2[t], bb1=ab2[t+256], bb2=ab2[t+512];
  float o_[4][3];
  #pragma unroll
  for (int r=0;r<4;++r){
    o_[r][0]=acc[r][0]+bb0; o_[r][1]=acc[r][1]+bb1; o_[r][2]=acc[r][2]+bb2;
  }
  #pragma unroll
  for (int r=0;r<4;++r)
    red[r][t] = make_float2(o_[r][0]+o_[r][1]+o_[r][2],
                            o_[r][0]*o_[r][0]+o_[r][1]*o_[r][1]+o_[r][2]*o_[r][2]);
  __syncthreads();
  int w = t>>6, lane = t&63;
  float s=0.f, s2=0.f;
  #pragma unroll
  for (int i=0;i<4;++i){ float2 v = red[w][lane + i*64]; s += v.x; s2 += v.y; }
  #pragma unroll
  for (int mk=1; mk<64; mk<<=1){
    s  += __shfl_xor(s, mk, 64);
    s2 += __shfl_xor(s2, mk, 64);
  }
  if (lane == 0){
    float mu = s*(1.f/768.f);
    float var = s2*(1.f/768.f) - mu*mu;
    sst[w] = make_float2(mu, 1.0f/sqrtf(var+EPS));
  }
  __syncthreads();
  float g0=ag2[t], g1v=ag2[t+256], g2v=ag2[t+512];
  float c0=abt2[t], c1=abt2[t+256], c2=abt2[t+512];
  #pragma unroll
  for (int r=0;r<4;++r){
    float mu = sst[r].x, iv = sst[r].y;
    float* ap = agg + (size_t)(row0+r)*768;
    ap[t]     = (o_[r][0]-mu)*iv*g0 + c0;
    ap[t+256] = (o_[r][1]-mu)*iv*g1v + c1;
    ap[t+512] = (o_[r][2]-mu)*iv*g2v + c2;
  }
}

// ---------------------------------------------------------------------------
// K3: ctx GEMM (h'@W2) + full epilogue -> out (fused final combine)
// grid: 256 blocks x 256 (64 rows/block, wave per 16-row tile, 48 col tiles)
// ---------------------------------------------------------------------------
__global__ __launch_bounds__(256) void k_final(
  const unsigned short* __restrict__ hprime, const unsigned short* __restrict__ W2T,
  const float* __restrict__ S1, const float* __restrict__ S2,
  const float* __restrict__ g2, const float* __restrict__ b2, const float* __restrict__ bt2,
  const float* __restrict__ features, const int* __restrict__ labels,
  const float* __restrict__ cnt, const float* __restrict__ agg,
  float* __restrict__ out)
{
  int t=threadIdx.x; int lane=t&63; int w=t>>6; int l15=lane&15, l4=lane>>4;
  int rowt = blockIdx.x*64 + w*16;
  const v8s* hv = reinterpret_cast<const v8s*>(hprime);
  v8s af0 = hv[(rowt+l15)*8 + l4];
  v8s af1 = hv[(rowt+l15)*8 + 4 + l4];
  float s1r[4], s2r[4], cntr[4]; int labr[4], br[4];
  #pragma unroll
  for (int r=0;r<4;++r){
    int row = rowt + l4*4 + r;
    s1r[r]=S1[row]; s2r[r]=S2[row];
    labr[r]=labels[row]; br[r]=row>>12;
    cntr[r]=cnt[br[r]*64 + labr[r]];
  }
  const v8s* wtv = reinterpret_cast<const v8s*>(W2T);
  for (int tc=0;tc<48;++tc){
    v8s bf0 = wtv[(tc*16+l15)*8 + l4];
    v8s bf1 = wtv[(tc*16+l15)*8 + 4 + l4];
    v4f acc = (v4f){0.f,0.f,0.f,0.f};
    acc = __builtin_amdgcn_mfma_f32_16x16x32_bf16(af0, bf0, acc, 0,0,0);
    acc = __builtin_amdgcn_mfma_f32_16x16x32_bf16(af1, bf1, acc, 0,0,0);
    int c = tc*16 + l15;
    float g2c=g2[c], b2c=b2[c], bt2c=bt2[c];
    #pragma unroll
    for (int r=0;r<4;++r){
      int row = rowt + l4*4 + r;
      float ctxv = 0.1f*(g2c*((acc[r] + b2c*s1r[r] - s2r[r])*0.125f) + bt2c);
      size_t o = (size_t)row*768 + c;
      float f = features[o];
      float av = agg[((size_t)(br[r]*64 + labr[r]))*768 + c];
      float enh = (cntr[r] >= 2.0f) ? (0.9f*f + 0.1f*av) : f;
      out[o] = enh + ctxv;
    }
  }
}

// ---------------------------------------------------------------------------
extern "C" void kernel_launch(void* const* d_in, const int* in_sizes, int n_in,
                              void* d_out, int out_size, void* d_ws, size_t ws_size,
                              hipStream_t stream) {
  const float* coords   = (const float*)d_in[0];
  const float* features = (const float*)d_in[1];
  const int*   labels   = (const int*)  d_in[2];
  const float* W1  = (const float*)d_in[3];
  const float* b1  = (const float*)d_in[4];
  const float* g1  = (const float*)d_in[5];
  const float* bt1 = (const float*)d_in[6];
  const float* W2  = (const float*)d_in[7];
  const float* b2  = (const float*)d_in[8];
  const float* g2  = (const float*)d_in[9];
  const float* bt2 = (const float*)d_in[10];
  const float* A1  = (const float*)d_in[11];
  const float* ab1 = (const float*)d_in[12];
  const float* ag1 = (const float*)d_in[13];
  const float* abt1= (const float*)d_in[14];
  const float* A2  = (const float*)d_in[15];
  const float* ab2 = (const float*)d_in[16];
  const float* ag2 = (const float*)d_in[17];
  const float* abt2= (const float*)d_in[18];

  char* ws = (char*)d_ws;
  size_t off = 0;
  auto alloc = [&](size_t bytes){ size_t o = off; off = (off + bytes + 255) & ~(size_t)255; return o; };
  float*          geom   = (float*)(ws + alloc((size_t)131072*4*4));
  unsigned short* hprime = (unsigned short*)(ws + alloc((size_t)16384*64*2));
  float*          S1w    = (float*)(ws + alloc(16384*4));
  float*          S2w    = (float*)(ws + alloc(16384*4));
  unsigned short* W2T    = (unsigned short*)(ws + alloc(768*64*2));
  unsigned short* Gm     = (unsigned short*)(ws + alloc(64*64*2));
  float*          w2bar  = (float*)(ws + alloc(64*4));
  float*          ubar   = (float*)(ws + alloc(64*4));
  float*          scal   = (float*)(ws + alloc(2*4));
  float*          cntw   = (float*)(ws + alloc(4*64*4));
  float*          agg    = (float*)(ws + alloc((size_t)4*64*768*4));
  unsigned short* A1bf   = (unsigned short*)(ws + alloc((size_t)98304*2));
  unsigned short* A2bf   = (unsigned short*)(ws + alloc((size_t)98304*2));
  unsigned short* ahbuf  = (unsigned short*)(ws + alloc((size_t)256*128*2));
  unsigned short* idxbuf = (unsigned short*)(ws + alloc((size_t)4*4096*2));
  int*            offsb  = (int*)(ws + alloc(256*4));
  float*          meanb  = (float*)(ws + alloc((size_t)256*768*4));

  k_prep   <<<dim3(305), dim3(256), 0, stream>>>(W2, b2, Gm, w2bar, ubar, scal, W2T,
                                                 A1, A2, A1bf, A2bf);
  k_sortidx<<<dim3(4),   dim3(256), 0, stream>>>(labels, idxbuf, offsb, cntw);
  k_segsum2<<<dim3(768), dim3(256), 0, stream>>>(features, idxbuf, offsb, cntw, meanb);
  k_mlp1   <<<dim3(64),  dim3(256), 0, stream>>>(meanb, A1bf, ab1, ag1, abt1, ahbuf);
  k_mlp2   <<<dim3(64),  dim3(256), 0, stream>>>(ahbuf, A2bf, ab2, ag2, abt2, agg);
  k_knn    <<<dim3(256), dim3(1024),0, stream>>>(coords, geom);
  k_hbuild <<<dim3(512), dim3(256), 0, stream>>>(geom, W1, b1, g1, bt1, Gm, w2bar, ubar, scal,
                                                 hprime, S1w, S2w);
  k_final  <<<dim3(256), dim3(256), 0, stream>>>(hprime, W2T, S1w, S2w, g2, b2, bt2,
                                                 features, labels, cntw, agg, (float*)d_out);
}